// Round 7
// baseline (1486.751 us; speedup 1.0000x reference)
//
#include <hip/hip_runtime.h>
#include <stdint.h>

#define MROWS 131072                     // 2048 windows * 64 tokens
#define LOG2E 1.44269504088896340736f
#define QSCALE 0.17677669529663688110f   // 32^-0.5

typedef __bf16 bf16x8 __attribute__((ext_vector_type(8)));
typedef float f32x4 __attribute__((ext_vector_type(4)));
typedef int i32x4 __attribute__((ext_vector_type(4)));
typedef unsigned short u16;
typedef u16 u16x4 __attribute__((ext_vector_type(4)));
typedef u16 u16x8 __attribute__((ext_vector_type(8)));

#define GLD16(gp, lp) __builtin_amdgcn_global_load_lds( \
    (const __attribute__((address_space(1))) void*)(gp), \
    (__attribute__((address_space(3))) void*)(lp), 16, 0, 0)

static __device__ __forceinline__ u16 f2bf(float f) {
    uint32_t u = __builtin_bit_cast(uint32_t, f);
    u += 0x7FFFu + ((u >> 16) & 1u);
    return (u16)(u >> 16);
}
static __device__ __forceinline__ float bf2f(u16 h) {
    uint32_t u = ((uint32_t)h) << 16;
    return __builtin_bit_cast(float, u);
}
static __device__ __forceinline__ float shflx(float v, int m) {
    return __shfl_xor(v, m, 64);
}
// bijective XCD swizzle: 4096 wgs, 8 XCDs, 512-wg contiguous chunk per XCD
static __device__ __forceinline__ int swz4096(int bid) {
    return (bid & 7) * 512 + (bid >> 3);
}

// ---------------- setup kernels ----------------
__global__ void wt_plain(const float* __restrict__ W, int ldW, int colOff,
                         u16* __restrict__ WT, int K) {
    int idx = blockIdx.x * 256 + threadIdx.x;
    int n = idx / K, k = idx - n * K;
    WT[idx] = f2bf(W[(size_t)k * ldW + colOff + n]);
}
__global__ void wt_split(const float* __restrict__ W, int ldW, int colOff,
                         u16* __restrict__ WTh, u16* __restrict__ WTl, int K) {
    int idx = blockIdx.x * 256 + threadIdx.x;
    int n = idx / K, k = idx - n * K;
    float v = W[(size_t)k * ldW + colOff + n];
    u16 h = f2bf(v);
    WTh[idx] = h;
    WTl[idx] = f2bf(v - bf2f(h));
}
// combined (rel-pos bias + shift mask), stored TRANSPOSED: cmb[wmod][h][j][i]
__global__ void cmb_pre(const float* __restrict__ table, const float* __restrict__ mask,
                        float* __restrict__ cmb) {
    int wmod = blockIdx.x, h = blockIdx.y;
    float* outp = cmb + (((size_t)wmod * 16 + h) << 12);
    const float* mp = mask + ((size_t)wmod << 12);
    for (int e = threadIdx.x; e < 4096; e += 256) {
        int j = e >> 6, i = e & 63;
        int idx = ((i >> 3) - (j >> 3) + 7) * 15 + ((i & 7) - (j & 7) + 7);
        outp[e] = table[idx * 16 + h] + mp[i * 64 + j];
    }
}

// ---------------- Q/K GEMM: A fp32 (reg-staged -> bf16 LDS), B direct from L2
__global__ __launch_bounds__(256) void gemm_qk(
    const float* __restrict__ A, const u16* __restrict__ BT,
    const float* __restrict__ bias, u16* __restrict__ outp, float scale)
{
    __shared__ u16 As[128 * 64];
    const int tid = threadIdx.x;
    const int l = tid & 63, w = tid >> 6;
    const int al = l & 15, g = l >> 4;
    const int wr = w >> 1, wc = w & 1;
    const int wg = swz4096(blockIdx.x);
    const int n0 = (wg & 3) * 128, m0 = (wg >> 2) * 128;
    const int srow = tid >> 3, sc8 = (tid & 7) * 8;
    const u16* bbase = BT + (size_t)(n0 + wc*64 + al) * 512 + g*8;
    f32x4 acc[4][4] = {};

    for (int kk = 0; kk < 512; kk += 64) {
        #pragma unroll
        for (int r = 0; r < 4; ++r) {
            int row = r * 32 + srow;
            const float* ap = A + (size_t)(m0 + row) * 512 + kk + sc8;
            f32x4 v0 = *(const f32x4*)(ap);
            f32x4 v1 = *(const f32x4*)(ap + 4);
            u16x8 hv;
            hv[0]=f2bf(v0[0]); hv[1]=f2bf(v0[1]); hv[2]=f2bf(v0[2]); hv[3]=f2bf(v0[3]);
            hv[4]=f2bf(v1[0]); hv[5]=f2bf(v1[1]); hv[6]=f2bf(v1[2]); hv[7]=f2bf(v1[3]);
            *(u16x8*)&As[row * 64 + sc8] = hv;
        }
        __syncthreads();
        #pragma unroll
        for (int kt = 0; kt < 2; ++kt) {
            bf16x8 af[4], bfr[4];
            #pragma unroll
            for (int nt = 0; nt < 4; ++nt)
                bfr[nt] = *(const bf16x8*)(bbase + (size_t)nt*16*512 + kk + kt*32);
            #pragma unroll
            for (int mt = 0; mt < 4; ++mt)
                af[mt] = *(const bf16x8*)&As[(wr*64 + mt*16 + al) * 64 + kt*32 + g*8];
            #pragma unroll
            for (int mt = 0; mt < 4; ++mt)
                #pragma unroll
                for (int nt = 0; nt < 4; ++nt)
                    acc[mt][nt] = __builtin_amdgcn_mfma_f32_16x16x32_bf16(af[mt], bfr[nt], acc[mt][nt], 0, 0, 0);
        }
        __syncthreads();
    }
    #pragma unroll
    for (int nt = 0; nt < 4; ++nt) {
        int col = n0 + wc*64 + nt*16 + al;
        float bv = bias[col];
        #pragma unroll
        for (int mt = 0; mt < 4; ++mt)
            #pragma unroll
            for (int rg = 0; rg < 4; ++rg) {
                size_t row = (size_t)(m0 + wr*64 + mt*16 + g*4 + rg);
                outp[row * 512 + col] = f2bf((acc[mt][nt][rg] + bv) * scale);
            }
    }
}

// ---------------- V GEMM: BK=32, A fp32 reg-staged split hi/lo (LDS), B hi/lo direct from L2
// Output: V^T per head, layout [window][h][d(32)][k(64)], hi/lo
__global__ __launch_bounds__(256) void gemm_v(
    const float* __restrict__ A,
    const u16* __restrict__ BTh, const u16* __restrict__ BTl,
    const float* __restrict__ bias,
    u16* __restrict__ out1, u16* __restrict__ out2)
{
    __shared__ u16 Ah[128*32], Alo[128*32];
    const int tid = threadIdx.x;
    const int l = tid & 63, w = tid >> 6;
    const int al = l & 15, g = l >> 4;
    const int wr = w >> 1, wc = w & 1;
    const int wg = swz4096(blockIdx.x);
    const int n0 = (wg & 3) * 128, m0 = (wg >> 2) * 128;
    const int srow = tid >> 2, sc8 = (tid & 3) * 8;
    const size_t brow = (size_t)(n0 + wc*64 + al) * 512 + g*8;
    f32x4 acc[4][4] = {};

    for (int kk = 0; kk < 512; kk += 32) {
        #pragma unroll
        for (int r = 0; r < 2; ++r) {
            int row = r * 64 + srow;
            const float* ap = A + (size_t)(m0 + row) * 512 + kk + sc8;
            f32x4 v0 = *(const f32x4*)(ap);
            f32x4 v1 = *(const f32x4*)(ap + 4);
            u16x8 hv, lv;
            #pragma unroll
            for (int c = 0; c < 4; ++c) {
                u16 hh = f2bf(v0[c]); hv[c] = hh; lv[c] = f2bf(v0[c] - bf2f(hh));
            }
            #pragma unroll
            for (int c = 0; c < 4; ++c) {
                u16 hh = f2bf(v1[c]); hv[4+c] = hh; lv[4+c] = f2bf(v1[c] - bf2f(hh));
            }
            *(u16x8*)&Ah[row * 32 + sc8]  = hv;
            *(u16x8*)&Alo[row * 32 + sc8] = lv;
        }
        __syncthreads();
        {
            bf16x8 ah[4], alo4[4], bh[4], bl[4];
            #pragma unroll
            for (int nt = 0; nt < 4; ++nt) {
                bh[nt] = *(const bf16x8*)(BTh + brow + (size_t)nt*16*512 + kk);
                bl[nt] = *(const bf16x8*)(BTl + brow + (size_t)nt*16*512 + kk);
            }
            #pragma unroll
            for (int mt = 0; mt < 4; ++mt) {
                ah[mt]   = *(const bf16x8*)&Ah[(wr*64 + mt*16 + al) * 32 + g*8];
                alo4[mt] = *(const bf16x8*)&Alo[(wr*64 + mt*16 + al) * 32 + g*8];
            }
            #pragma unroll
            for (int mt = 0; mt < 4; ++mt)
                #pragma unroll
                for (int nt = 0; nt < 4; ++nt) {
                    acc[mt][nt] = __builtin_amdgcn_mfma_f32_16x16x32_bf16(ah[mt],   bh[nt], acc[mt][nt], 0, 0, 0);
                    acc[mt][nt] = __builtin_amdgcn_mfma_f32_16x16x32_bf16(ah[mt],   bl[nt], acc[mt][nt], 0, 0, 0);
                    acc[mt][nt] = __builtin_amdgcn_mfma_f32_16x16x32_bf16(alo4[mt], bh[nt], acc[mt][nt], 0, 0, 0);
                }
        }
        __syncthreads();
    }
    #pragma unroll
    for (int nt = 0; nt < 4; ++nt) {
        int col = n0 + wc*64 + nt*16 + al;
        int hh_ = col >> 5, d = col & 31;
        float bv = bias[col];
        #pragma unroll
        for (int mt = 0; mt < 4; ++mt) {
            int row0 = m0 + wr*64 + mt*16 + g*4;
            int window = row0 >> 6, k0 = row0 & 63;
            size_t off = ((size_t)window << 15) + (hh_ << 11) + (d << 6) + k0;
            u16x4 hv, lv;
            #pragma unroll
            for (int rg = 0; rg < 4; ++rg) {
                float v = acc[mt][nt][rg] + bv;
                u16 hb = f2bf(v);
                hv[rg] = hb;
                lv[rg] = f2bf(v - bf2f(hb));
            }
            *(u16x4*)(out1 + off) = hv;
            *(u16x4*)(out2 + off) = lv;
        }
    }
}

// ---------------- proj GEMM: BK=32, A hi/lo via global_load_lds, B hi/lo direct from L2
__global__ __launch_bounds__(256) void gemm_proj(
    const u16* __restrict__ A1, const u16* __restrict__ A2,
    const u16* __restrict__ BTh, const u16* __restrict__ BTl,
    const float* __restrict__ bias, float* __restrict__ outp)
{
    __shared__ u16 Ah[128*32], Alo[128*32];
    const int tid = threadIdx.x;
    const int l = tid & 63, w = tid >> 6;
    const int al = l & 15, g = l >> 4;
    const int wr = w >> 1, wc = w & 1;
    const int wg = swz4096(blockIdx.x);
    const int n0 = (wg & 3) * 128, m0 = (wg >> 2) * 128;
    const int srow = tid >> 2, sc8 = (tid & 3) * 8;
    const size_t brow = (size_t)(n0 + wc*64 + al) * 512 + g*8;
    f32x4 acc[4][4] = {};

    for (int kk = 0; kk < 512; kk += 32) {
        #pragma unroll
        for (int r = 0; r < 2; ++r) {
            int row = r * 64 + srow;
            size_t aoff = (size_t)(m0 + row) * 512 + kk + sc8;
            int loff = row * 32 + sc8;
            GLD16(A1 + aoff, &Ah[loff]);
            GLD16(A2 + aoff, &Alo[loff]);
        }
        __syncthreads();
        {
            bf16x8 ah[4], alo4[4], bh[4], bl[4];
            #pragma unroll
            for (int nt = 0; nt < 4; ++nt) {
                bh[nt] = *(const bf16x8*)(BTh + brow + (size_t)nt*16*512 + kk);
                bl[nt] = *(const bf16x8*)(BTl + brow + (size_t)nt*16*512 + kk);
            }
            #pragma unroll
            for (int mt = 0; mt < 4; ++mt) {
                ah[mt]   = *(const bf16x8*)&Ah[(wr*64 + mt*16 + al) * 32 + g*8];
                alo4[mt] = *(const bf16x8*)&Alo[(wr*64 + mt*16 + al) * 32 + g*8];
            }
            #pragma unroll
            for (int mt = 0; mt < 4; ++mt)
                #pragma unroll
                for (int nt = 0; nt < 4; ++nt) {
                    acc[mt][nt] = __builtin_amdgcn_mfma_f32_16x16x32_bf16(ah[mt],   bh[nt], acc[mt][nt], 0, 0, 0);
                    acc[mt][nt] = __builtin_amdgcn_mfma_f32_16x16x32_bf16(ah[mt],   bl[nt], acc[mt][nt], 0, 0, 0);
                    acc[mt][nt] = __builtin_amdgcn_mfma_f32_16x16x32_bf16(alo4[mt], bh[nt], acc[mt][nt], 0, 0, 0);
                }
        }
        __syncthreads();
    }
    #pragma unroll
    for (int nt = 0; nt < 4; ++nt) {
        int col = n0 + wc*64 + nt*16 + al;
        float bv = bias[col];
        #pragma unroll
        for (int mt = 0; mt < 4; ++mt)
            #pragma unroll
            for (int rg = 0; rg < 4; ++rg) {
                size_t row = (size_t)(m0 + wr*64 + mt*16 + g*4 + rg);
                outp[row * 512 + col] = acc[mt][nt][rg] + bv;
            }
    }
}

// ---------------- fused window attention ----------------
// grid (2048 windows, 4 head-groups); wave w handles head blockIdx.y*4 + w.
__global__ __launch_bounds__(256) void attn64(
    const u16* __restrict__ Q, const u16* __restrict__ Kb,
    const u16* __restrict__ Vth, const u16* __restrict__ Vtl,
    const float* __restrict__ cmb,
    u16* __restrict__ Ohi, u16* __restrict__ Olo)
{
    __shared__ u16 Ph[4][16 * 72];
    __shared__ u16 Pl[4][16 * 72];
    const int b = blockIdx.x;
    const int tid = threadIdx.x;
    const int l = tid & 63, w = tid >> 6;
    const int al = l & 15, g = l >> 4;
    const size_t rbase = (size_t)b * 64;
    const int h = blockIdx.y * 4 + w;
    const int co = h * 32;

    const u16* vth = Vth + ((size_t)b << 15) + (h << 11);
    const u16* vtl = Vtl + ((size_t)b << 15) + (h << 11);
    bf16x8 vhf[2][2], vlf[2][2];
    #pragma unroll
    for (int kt = 0; kt < 2; ++kt)
        #pragma unroll
        for (int dt = 0; dt < 2; ++dt) {
            int voff = ((dt*16 + al) << 6) + kt*32 + g*8;
            vhf[kt][dt] = *(const bf16x8*)(vth + voff);
            vlf[kt][dt] = *(const bf16x8*)(vtl + voff);
        }

    bf16x8 qf[4], kf[4];
    #pragma unroll
    for (int t = 0; t < 4; ++t) {
        qf[t] = *(const bf16x8*)(Q  + (rbase + t*16 + al) * 512 + co + g*8);
        kf[t] = *(const bf16x8*)(Kb + (rbase + t*16 + al) * 512 + co + g*8);
    }
    f32x4 s[4][4] = {};
    #pragma unroll
    for (int mt = 0; mt < 4; ++mt)
        #pragma unroll
        for (int nt = 0; nt < 4; ++nt)
            s[mt][nt] = __builtin_amdgcn_mfma_f32_16x16x32_bf16(qf[mt], kf[nt], s[mt][nt], 0, 0, 0);

    const float* cp = cmb + ((((size_t)(b & 63)) * 16 + h) << 12);
    #pragma unroll
    for (int mt = 0; mt < 4; ++mt)
        #pragma unroll
        for (int nt = 0; nt < 4; ++nt) {
            f32x4 c4 = *(const f32x4*)(cp + ((nt*16 + al) << 6) + mt*16 + g*4);
            #pragma unroll
            for (int rg = 0; rg < 4; ++rg) s[mt][nt][rg] += c4[rg];
        }

    #pragma unroll
    for (int mt = 0; mt < 4; ++mt) {
        f32x4 m4 = s[mt][0];
        #pragma unroll
        for (int nt = 1; nt < 4; ++nt)
            #pragma unroll
            for (int c = 0; c < 4; ++c) m4[c] = fmaxf(m4[c], s[mt][nt][c]);
        #pragma unroll
        for (int d = 1; d < 16; d <<= 1)
            #pragma unroll
            for (int c = 0; c < 4; ++c) m4[c] = fmaxf(m4[c], shflx(m4[c], d));
        #pragma unroll
        for (int nt = 0; nt < 4; ++nt)
            #pragma unroll
            for (int rg = 0; rg < 4; ++rg)
                s[mt][nt][rg] = exp2f((s[mt][nt][rg] - m4[rg]) * LOG2E);
        f32x4 s4 = s[mt][0];
        #pragma unroll
        for (int nt = 1; nt < 4; ++nt) s4 += s[mt][nt];
        #pragma unroll
        for (int d = 1; d < 16; d <<= 1)
            #pragma unroll
            for (int c = 0; c < 4; ++c) s4[c] += shflx(s4[c], d);
        #pragma unroll
        for (int nt = 0; nt < 4; ++nt)
            #pragma unroll
            for (int rg = 0; rg < 4; ++rg) {
                float p = s[mt][nt][rg];
                u16 ph = f2bf(p);
                int off = (g*4 + rg) * 72 + nt*16 + al;
                Ph[w][off] = ph;
                Pl[w][off] = f2bf(p - bf2f(ph));
            }
        bf16x8 pah[2], pal[2];
        #pragma unroll
        for (int kt = 0; kt < 2; ++kt) {
            pah[kt] = *(const bf16x8*)&Ph[w][al * 72 + kt*32 + g*8];
            pal[kt] = *(const bf16x8*)&Pl[w][al * 72 + kt*32 + g*8];
        }
        f32x4 o[2] = {};
        #pragma unroll
        for (int dt = 0; dt < 2; ++dt)
            #pragma unroll
            for (int kt = 0; kt < 2; ++kt) {
                o[dt] = __builtin_amdgcn_mfma_f32_16x16x32_bf16(pah[kt], vhf[kt][dt], o[dt], 0, 0, 0);
                o[dt] = __builtin_amdgcn_mfma_f32_16x16x32_bf16(pah[kt], vlf[kt][dt], o[dt], 0, 0, 0);
                o[dt] = __builtin_amdgcn_mfma_f32_16x16x32_bf16(pal[kt], vhf[kt][dt], o[dt], 0, 0, 0);
            }
        #pragma unroll
        for (int dt = 0; dt < 2; ++dt)
            #pragma unroll
            for (int rg = 0; rg < 4; ++rg) {
                float v = o[dt][rg] * (1.0f / s4[rg]);
                size_t off = (rbase + mt*16 + g*4 + rg) * 512 + co + dt*16 + al;
                u16 hh = f2bf(v);
                Ohi[off] = hh;
                Olo[off] = f2bf(v - bf2f(hh));
            }
    }
}

// ---------------- launch ----------------
extern "C" void kernel_launch(void* const* d_in, const int* in_sizes, int n_in,
                              void* d_out, int out_size, void* d_ws, size_t ws_size,
                              hipStream_t stream)
{
    const float* x      = (const float*)d_in[0];
    const float* y      = (const float*)d_in[1];
    const float* mask   = (const float*)d_in[2];
    const float* W_q    = (const float*)d_in[3];
    const float* b_q    = (const float*)d_in[4];
    const float* W_kv   = (const float*)d_in[5];
    const float* b_kv   = (const float*)d_in[6];
    const float* W_proj = (const float*)d_in[7];
    const float* b_proj = (const float*)d_in[8];
    const float* table  = (const float*)d_in[9];

    char* ws = (char*)d_ws;
    const size_t SEG = (size_t)MROWS * 512 * sizeof(u16);   // 128 MB
    u16* Qs     = (u16*)(ws);              // aliased by O_hi after attention
    u16* Ks     = (u16*)(ws + SEG);        // aliased by O_lo after attention
    u16* Vth    = (u16*)(ws + 2 * SEG);    // V^T hi [win][h][d][k]
    u16* Vtl    = (u16*)(ws + 3 * SEG);    // V^T lo
    u16* wqT    = (u16*)(ws + 4 * SEG);
    u16* wkvKT  = wqT    + 512 * 512;
    u16* wkvVTh = wkvKT  + 512 * 512;
    u16* wkvVTl = wkvVTh + 512 * 512;
    u16* wprTh  = wkvVTl + 512 * 512;
    u16* wprTl  = wprTh  + 512 * 512;
    float* cmb  = (float*)(wprTl + 512 * 512);   // 64*16*4096*4B = 16 MB

    wt_plain<<<1024, 256, 0, stream>>>(W_q, 512, 0, wqT, 512);
    wt_plain<<<1024, 256, 0, stream>>>(W_kv, 1024, 0, wkvKT, 512);
    wt_split<<<1024, 256, 0, stream>>>(W_kv, 1024, 512, wkvVTh, wkvVTl, 512);
    wt_split<<<1024, 256, 0, stream>>>(W_proj, 512, 0, wprTh, wprTl, 512);
    cmb_pre<<<dim3(64, 16), 256, 0, stream>>>(table, mask, cmb);

    gemm_qk<<<4096, 256, 0, stream>>>(x, wqT, b_q, Qs, QSCALE);
    gemm_qk<<<4096, 256, 0, stream>>>(y, wkvKT, b_kv, Ks, 1.0f);
    gemm_v<<<4096, 256, 0, stream>>>(y, wkvVTh, wkvVTl, b_kv + 512, Vth, Vtl);
    attn64<<<dim3(2048, 4), 256, 0, stream>>>(Qs, Ks, Vth, Vtl, cmb, Qs, Ks);
    gemm_proj<<<4096, 256, 0, stream>>>(Qs, Ks, wprTh, wprTl, b_proj, (float*)d_out);
}

// Round 8
// 930.179 us; speedup vs baseline: 1.5983x; 1.5983x over previous
//
#include <hip/hip_runtime.h>
#include <stdint.h>

#define MROWS 131072                     // 2048 windows * 64 tokens
#define LOG2E 1.44269504088896340736f
#define QSCALE 0.17677669529663688110f   // 32^-0.5

typedef _Float16 f16x8 __attribute__((ext_vector_type(8)));
typedef float f32x4 __attribute__((ext_vector_type(4)));
typedef unsigned short u16;
typedef u16 u16x4 __attribute__((ext_vector_type(4)));
typedef u16 u16x8 __attribute__((ext_vector_type(8)));

#define GLD16(gp, lp) __builtin_amdgcn_global_load_lds( \
    (const __attribute__((address_space(1))) void*)(gp), \
    (__attribute__((address_space(3))) void*)(lp), 16, 0, 0)

static __device__ __forceinline__ u16 f2h(float f) {
    _Float16 h = (_Float16)f;             // RNE
    return __builtin_bit_cast(unsigned short, h);
}
static __device__ __forceinline__ float shflx(float v, int m) {
    return __shfl_xor(v, m, 64);
}
// bijective XCD swizzle: 4096 wgs, 8 XCDs, 512-wg contiguous chunk per XCD
static __device__ __forceinline__ int swz4096(int bid) {
    return (bid & 7) * 512 + (bid >> 3);
}

// ---------------- setup kernels ----------------
__global__ void wt_f16(const float* __restrict__ W, int ldW, int colOff,
                       u16* __restrict__ WT, int K) {
    int idx = blockIdx.x * 256 + threadIdx.x;
    int n = idx / K, k = idx - n * K;
    WT[idx] = f2h(W[(size_t)k * ldW + colOff + n]);
}
// combined (rel-pos bias + shift mask), stored TRANSPOSED: cmb[wmod][h][j][i]
__global__ void cmb_pre(const float* __restrict__ table, const float* __restrict__ mask,
                        float* __restrict__ cmb) {
    int wmod = blockIdx.x, h = blockIdx.y;
    float* outp = cmb + (((size_t)wmod * 16 + h) << 12);
    const float* mp = mask + ((size_t)wmod << 12);
    for (int e = threadIdx.x; e < 4096; e += 256) {
        int j = e >> 6, i = e & 63;
        int idx = ((i >> 3) - (j >> 3) + 7) * 15 + ((i & 7) - (j & 7) + 7);
        outp[e] = table[idx * 16 + h] + mp[i * 64 + j];
    }
}

// ---------------- Q/K GEMM: A fp32 (reg-staged -> fp16 LDS), B via global_load_lds
__global__ __launch_bounds__(256) void gemm_qk(
    const float* __restrict__ A, const u16* __restrict__ BT,
    const float* __restrict__ bias, u16* __restrict__ outp, float scale)
{
    __shared__ u16 As[128 * 64];
    __shared__ u16 Bs[128 * 64];
    const int tid = threadIdx.x;
    const int l = tid & 63, w = tid >> 6;
    const int al = l & 15, g = l >> 4;
    const int wr = w >> 1, wc = w & 1;
    const int wg = swz4096(blockIdx.x);
    const int n0 = (wg & 3) * 128, m0 = (wg >> 2) * 128;
    const int srow = tid >> 3, sc8 = (tid & 7) * 8;
    f32x4 acc[4][4] = {};

    for (int kk = 0; kk < 512; kk += 64) {
        #pragma unroll
        for (int r = 0; r < 4; ++r) {
            int row = r * 32 + srow;
            GLD16(BT + (size_t)(n0 + row) * 512 + kk + sc8, &Bs[row * 64 + sc8]);
            const float* ap = A + (size_t)(m0 + row) * 512 + kk + sc8;
            f32x4 v0 = *(const f32x4*)(ap);
            f32x4 v1 = *(const f32x4*)(ap + 4);
            u16x8 hv;
            hv[0]=f2h(v0[0]); hv[1]=f2h(v0[1]); hv[2]=f2h(v0[2]); hv[3]=f2h(v0[3]);
            hv[4]=f2h(v1[0]); hv[5]=f2h(v1[1]); hv[6]=f2h(v1[2]); hv[7]=f2h(v1[3]);
            *(u16x8*)&As[row * 64 + sc8] = hv;
        }
        __syncthreads();
        #pragma unroll
        for (int kt = 0; kt < 2; ++kt) {
            f16x8 af[4], bfr[4];
            #pragma unroll
            for (int mt = 0; mt < 4; ++mt)
                af[mt] = *(const f16x8*)&As[(wr*64 + mt*16 + al) * 64 + kt*32 + g*8];
            #pragma unroll
            for (int nt = 0; nt < 4; ++nt)
                bfr[nt] = *(const f16x8*)&Bs[(wc*64 + nt*16 + al) * 64 + kt*32 + g*8];
            #pragma unroll
            for (int mt = 0; mt < 4; ++mt)
                #pragma unroll
                for (int nt = 0; nt < 4; ++nt)
                    acc[mt][nt] = __builtin_amdgcn_mfma_f32_16x16x32_f16(af[mt], bfr[nt], acc[mt][nt], 0, 0, 0);
        }
        __syncthreads();
    }
    #pragma unroll
    for (int nt = 0; nt < 4; ++nt) {
        int col = n0 + wc*64 + nt*16 + al;
        float bv = bias[col];
        #pragma unroll
        for (int mt = 0; mt < 4; ++mt)
            #pragma unroll
            for (int rg = 0; rg < 4; ++rg) {
                size_t row = (size_t)(m0 + wr*64 + mt*16 + g*4 + rg);
                outp[row * 512 + col] = f2h((acc[mt][nt][rg] + bv) * scale);
            }
    }
}

// ---------------- V GEMM: BK=32, A fp32 reg-staged -> fp16, B via gld_lds
// Output: V^T per head, layout [window][h][d(32)][k(64)], fp16
__global__ __launch_bounds__(256, 4) void gemm_v(
    const float* __restrict__ A, const u16* __restrict__ BT,
    const float* __restrict__ bias, u16* __restrict__ outp)
{
    __shared__ u16 As[128*32], Bs[128*32];
    const int tid = threadIdx.x;
    const int l = tid & 63, w = tid >> 6;
    const int al = l & 15, g = l >> 4;
    const int wr = w >> 1, wc = w & 1;
    const int wg = swz4096(blockIdx.x);
    const int n0 = (wg & 3) * 128, m0 = (wg >> 2) * 128;
    const int srow = tid >> 2, sc8 = (tid & 3) * 8;
    f32x4 acc[4][4] = {};

    for (int kk = 0; kk < 512; kk += 32) {
        #pragma unroll
        for (int r = 0; r < 2; ++r) {
            int row = r * 64 + srow;
            GLD16(BT + (size_t)(n0 + row) * 512 + kk + sc8, &Bs[row * 32 + sc8]);
            const float* ap = A + (size_t)(m0 + row) * 512 + kk + sc8;
            f32x4 v0 = *(const f32x4*)(ap);
            f32x4 v1 = *(const f32x4*)(ap + 4);
            u16x8 hv;
            hv[0]=f2h(v0[0]); hv[1]=f2h(v0[1]); hv[2]=f2h(v0[2]); hv[3]=f2h(v0[3]);
            hv[4]=f2h(v1[0]); hv[5]=f2h(v1[1]); hv[6]=f2h(v1[2]); hv[7]=f2h(v1[3]);
            *(u16x8*)&As[row * 32 + sc8] = hv;
        }
        __syncthreads();
        {
            f16x8 af[4], bfr[4];
            #pragma unroll
            for (int mt = 0; mt < 4; ++mt)
                af[mt] = *(const f16x8*)&As[(wr*64 + mt*16 + al) * 32 + g*8];
            #pragma unroll
            for (int nt = 0; nt < 4; ++nt)
                bfr[nt] = *(const f16x8*)&Bs[(wc*64 + nt*16 + al) * 32 + g*8];
            #pragma unroll
            for (int mt = 0; mt < 4; ++mt)
                #pragma unroll
                for (int nt = 0; nt < 4; ++nt)
                    acc[mt][nt] = __builtin_amdgcn_mfma_f32_16x16x32_f16(af[mt], bfr[nt], acc[mt][nt], 0, 0, 0);
        }
        __syncthreads();
    }
    #pragma unroll
    for (int nt = 0; nt < 4; ++nt) {
        int col = n0 + wc*64 + nt*16 + al;
        int hh_ = col >> 5, d = col & 31;
        float bv = bias[col];
        #pragma unroll
        for (int mt = 0; mt < 4; ++mt) {
            int row0 = m0 + wr*64 + mt*16 + g*4;
            int window = row0 >> 6, k0 = row0 & 63;
            size_t off = ((size_t)window << 15) + (hh_ << 11) + (d << 6) + k0;
            u16x4 hv;
            #pragma unroll
            for (int rg = 0; rg < 4; ++rg)
                hv[rg] = f2h(acc[mt][nt][rg] + bv);
            *(u16x4*)(outp + off) = hv;
        }
    }
}

// ---------------- proj GEMM: BK=32, A (fp16 O) + B via global_load_lds, fp32 out
__global__ __launch_bounds__(256, 4) void gemm_proj(
    const u16* __restrict__ A1, const u16* __restrict__ BT,
    const float* __restrict__ bias, float* __restrict__ outp)
{
    __shared__ u16 As[128*32], Bs[128*32];
    const int tid = threadIdx.x;
    const int l = tid & 63, w = tid >> 6;
    const int al = l & 15, g = l >> 4;
    const int wr = w >> 1, wc = w & 1;
    const int wg = swz4096(blockIdx.x);
    const int n0 = (wg & 3) * 128, m0 = (wg >> 2) * 128;
    const int srow = tid >> 2, sc8 = (tid & 3) * 8;
    f32x4 acc[4][4] = {};

    for (int kk = 0; kk < 512; kk += 32) {
        #pragma unroll
        for (int r = 0; r < 2; ++r) {
            int row = r * 64 + srow;
            size_t aoff = (size_t)(m0 + row) * 512 + kk + sc8;
            size_t boff = (size_t)(n0 + row) * 512 + kk + sc8;
            int loff = row * 32 + sc8;
            GLD16(A1 + aoff, &As[loff]);
            GLD16(BT + boff, &Bs[loff]);
        }
        __syncthreads();
        {
            f16x8 af[4], bfr[4];
            #pragma unroll
            for (int mt = 0; mt < 4; ++mt)
                af[mt] = *(const f16x8*)&As[(wr*64 + mt*16 + al) * 32 + g*8];
            #pragma unroll
            for (int nt = 0; nt < 4; ++nt)
                bfr[nt] = *(const f16x8*)&Bs[(wc*64 + nt*16 + al) * 32 + g*8];
            #pragma unroll
            for (int mt = 0; mt < 4; ++mt)
                #pragma unroll
                for (int nt = 0; nt < 4; ++nt)
                    acc[mt][nt] = __builtin_amdgcn_mfma_f32_16x16x32_f16(af[mt], bfr[nt], acc[mt][nt], 0, 0, 0);
        }
        __syncthreads();
    }
    #pragma unroll
    for (int nt = 0; nt < 4; ++nt) {
        int col = n0 + wc*64 + nt*16 + al;
        float bv = bias[col];
        #pragma unroll
        for (int mt = 0; mt < 4; ++mt)
            #pragma unroll
            for (int rg = 0; rg < 4; ++rg) {
                size_t row = (size_t)(m0 + wr*64 + mt*16 + g*4 + rg);
                outp[row * 512 + col] = acc[mt][nt][rg] + bv;
            }
    }
}

// ---------------- fused window attention (all fp16 fragments) ----------------
// grid (2048 windows, 4 head-groups); wave w handles head blockIdx.y*4 + w.
__global__ __launch_bounds__(256) void attn64(
    const u16* __restrict__ Q, const u16* __restrict__ Kb,
    const u16* __restrict__ Vth,
    const float* __restrict__ cmb,
    u16* __restrict__ Oout)
{
    __shared__ u16 Ph[4][16 * 72];
    const int b = blockIdx.x;
    const int tid = threadIdx.x;
    const int l = tid & 63, w = tid >> 6;
    const int al = l & 15, g = l >> 4;
    const size_t rbase = (size_t)b * 64;
    const int h = blockIdx.y * 4 + w;
    const int co = h * 32;

    const u16* vth = Vth + ((size_t)b << 15) + (h << 11);
    f16x8 vhf[2][2];
    #pragma unroll
    for (int kt = 0; kt < 2; ++kt)
        #pragma unroll
        for (int dt = 0; dt < 2; ++dt) {
            int voff = ((dt*16 + al) << 6) + kt*32 + g*8;
            vhf[kt][dt] = *(const f16x8*)(vth + voff);
        }

    f16x8 qf[4], kf[4];
    #pragma unroll
    for (int t = 0; t < 4; ++t) {
        qf[t] = *(const f16x8*)(Q  + (rbase + t*16 + al) * 512 + co + g*8);
        kf[t] = *(const f16x8*)(Kb + (rbase + t*16 + al) * 512 + co + g*8);
    }
    f32x4 s[4][4] = {};
    #pragma unroll
    for (int mt = 0; mt < 4; ++mt)
        #pragma unroll
        for (int nt = 0; nt < 4; ++nt)
            s[mt][nt] = __builtin_amdgcn_mfma_f32_16x16x32_f16(qf[mt], kf[nt], s[mt][nt], 0, 0, 0);

    const float* cp = cmb + ((((size_t)(b & 63)) * 16 + h) << 12);
    #pragma unroll
    for (int mt = 0; mt < 4; ++mt)
        #pragma unroll
        for (int nt = 0; nt < 4; ++nt) {
            f32x4 c4 = *(const f32x4*)(cp + ((nt*16 + al) << 6) + mt*16 + g*4);
            #pragma unroll
            for (int rg = 0; rg < 4; ++rg) s[mt][nt][rg] += c4[rg];
        }

    #pragma unroll
    for (int mt = 0; mt < 4; ++mt) {
        f32x4 m4 = s[mt][0];
        #pragma unroll
        for (int nt = 1; nt < 4; ++nt)
            #pragma unroll
            for (int c = 0; c < 4; ++c) m4[c] = fmaxf(m4[c], s[mt][nt][c]);
        #pragma unroll
        for (int d = 1; d < 16; d <<= 1)
            #pragma unroll
            for (int c = 0; c < 4; ++c) m4[c] = fmaxf(m4[c], shflx(m4[c], d));
        #pragma unroll
        for (int nt = 0; nt < 4; ++nt)
            #pragma unroll
            for (int rg = 0; rg < 4; ++rg)
                s[mt][nt][rg] = exp2f((s[mt][nt][rg] - m4[rg]) * LOG2E);
        f32x4 s4 = s[mt][0];
        #pragma unroll
        for (int nt = 1; nt < 4; ++nt) s4 += s[mt][nt];
        #pragma unroll
        for (int d = 1; d < 16; d <<= 1)
            #pragma unroll
            for (int c = 0; c < 4; ++c) s4[c] += shflx(s4[c], d);
        #pragma unroll
        for (int nt = 0; nt < 4; ++nt)
            #pragma unroll
            for (int rg = 0; rg < 4; ++rg) {
                int off = (g*4 + rg) * 72 + nt*16 + al;
                Ph[w][off] = f2h(s[mt][nt][rg]);
            }
        f16x8 pah[2];
        #pragma unroll
        for (int kt = 0; kt < 2; ++kt)
            pah[kt] = *(const f16x8*)&Ph[w][al * 72 + kt*32 + g*8];
        f32x4 o[2] = {};
        #pragma unroll
        for (int dt = 0; dt < 2; ++dt)
            #pragma unroll
            for (int kt = 0; kt < 2; ++kt)
                o[dt] = __builtin_amdgcn_mfma_f32_16x16x32_f16(pah[kt], vhf[kt][dt], o[dt], 0, 0, 0);
        #pragma unroll
        for (int dt = 0; dt < 2; ++dt)
            #pragma unroll
            for (int rg = 0; rg < 4; ++rg) {
                float v = o[dt][rg] * (1.0f / s4[rg]);
                size_t off = (rbase + mt*16 + g*4 + rg) * 512 + co + dt*16 + al;
                Oout[off] = f2h(v);
            }
    }
}

// ---------------- launch ----------------
extern "C" void kernel_launch(void* const* d_in, const int* in_sizes, int n_in,
                              void* d_out, int out_size, void* d_ws, size_t ws_size,
                              hipStream_t stream)
{
    const float* x      = (const float*)d_in[0];
    const float* y      = (const float*)d_in[1];
    const float* mask   = (const float*)d_in[2];
    const float* W_q    = (const float*)d_in[3];
    const float* b_q    = (const float*)d_in[4];
    const float* W_kv   = (const float*)d_in[5];
    const float* b_kv   = (const float*)d_in[6];
    const float* W_proj = (const float*)d_in[7];
    const float* b_proj = (const float*)d_in[8];
    const float* table  = (const float*)d_in[9];

    char* ws = (char*)d_ws;
    const size_t SEG = (size_t)MROWS * 512 * sizeof(u16);   // 128 MB
    u16* Qs     = (u16*)(ws);              // aliased by O after attention
    u16* Ks     = (u16*)(ws + SEG);
    u16* Vth    = (u16*)(ws + 2 * SEG);    // V^T [win][h][d][k], fp16
    u16* wqT    = (u16*)(ws + 3 * SEG);
    u16* wkvKT  = wqT    + 512 * 512;
    u16* wkvVT  = wkvKT  + 512 * 512;
    u16* wprT   = wkvVT  + 512 * 512;
    float* cmb  = (float*)(wprT + 512 * 512);   // 64*16*4096*4B = 16 MB

    wt_f16<<<1024, 256, 0, stream>>>(W_q, 512, 0, wqT, 512);
    wt_f16<<<1024, 256, 0, stream>>>(W_kv, 1024, 0, wkvKT, 512);
    wt_f16<<<1024, 256, 0, stream>>>(W_kv, 1024, 512, wkvVT, 512);
    wt_f16<<<1024, 256, 0, stream>>>(W_proj, 512, 0, wprT, 512);
    cmb_pre<<<dim3(64, 16), 256, 0, stream>>>(table, mask, cmb);

    gemm_qk<<<4096, 256, 0, stream>>>(x, wqT, b_q, Qs, QSCALE);
    gemm_qk<<<4096, 256, 0, stream>>>(y, wkvKT, b_kv, Ks, 1.0f);
    gemm_v<<<4096, 256, 0, stream>>>(y, wkvVT, b_kv + 512, Vth);
    attn64<<<dim3(2048, 4), 256, 0, stream>>>(Qs, Ks, Vth, cmb, Qs);
    gemm_proj<<<4096, 256, 0, stream>>>(Qs, wprT, b_proj, (float*)d_out);
}

// Round 9
// 829.208 us; speedup vs baseline: 1.7930x; 1.1218x over previous
//
#include <hip/hip_runtime.h>
#include <stdint.h>

#define MROWS 131072                     // 2048 windows * 64 tokens
#define LOG2E 1.44269504088896340736f
#define QSCALE 0.17677669529663688110f   // 32^-0.5

typedef _Float16 f16x8 __attribute__((ext_vector_type(8)));
typedef float f32x4 __attribute__((ext_vector_type(4)));
typedef unsigned short u16;
typedef u16 u16x4 __attribute__((ext_vector_type(4)));
typedef u16 u16x8 __attribute__((ext_vector_type(8)));

#define GLD16(gp, lp) __builtin_amdgcn_global_load_lds( \
    (const __attribute__((address_space(1))) void*)(gp), \
    (__attribute__((address_space(3))) void*)(lp), 16, 0, 0)

static __device__ __forceinline__ u16 f2h(float f) {
    _Float16 h = (_Float16)f;             // RNE
    return __builtin_bit_cast(unsigned short, h);
}
static __device__ __forceinline__ float shflx(float v, int m) {
    return __shfl_xor(v, m, 64);
}
// bijective XCD swizzle: 4096 wgs, 8 XCDs, 512-wg contiguous chunk per XCD
static __device__ __forceinline__ int swz4096(int bid) {
    return (bid & 7) * 512 + (bid >> 3);
}

// ---------------- setup kernels ----------------
__global__ void wt_f16(const float* __restrict__ W, int ldW, int colOff,
                       u16* __restrict__ WT, int K) {
    int idx = blockIdx.x * 256 + threadIdx.x;
    int n = idx / K, k = idx - n * K;
    WT[idx] = f2h(W[(size_t)k * ldW + colOff + n]);
}
// combined (rel-pos bias + shift mask), stored TRANSPOSED: cmb[wmod][h][j][i]
__global__ void cmb_pre(const float* __restrict__ table, const float* __restrict__ mask,
                        float* __restrict__ cmb) {
    int wmod = blockIdx.x, h = blockIdx.y;
    float* outp = cmb + (((size_t)wmod * 16 + h) << 12);
    const float* mp = mask + ((size_t)wmod << 12);
    for (int e = threadIdx.x; e < 4096; e += 256) {
        int j = e >> 6, i = e & 63;
        int idx = ((i >> 3) - (j >> 3) + 7) * 15 + ((i & 7) - (j & 7) + 7);
        outp[e] = table[idx * 16 + h] + mp[i * 64 + j];
    }
}

// ---------------- Q/K GEMM: A fp32 (reg-staged -> fp16 LDS), B via global_load_lds
__global__ __launch_bounds__(256) void gemm_qk(
    const float* __restrict__ A, const u16* __restrict__ BT,
    const float* __restrict__ bias, u16* __restrict__ outp, float scale)
{
    __shared__ u16 As[128 * 64];
    __shared__ u16 Bs[128 * 64];
    const int tid = threadIdx.x;
    const int l = tid & 63, w = tid >> 6;
    const int al = l & 15, g = l >> 4;
    const int wr = w >> 1, wc = w & 1;
    const int wg = swz4096(blockIdx.x);
    const int n0 = (wg & 3) * 128, m0 = (wg >> 2) * 128;
    const int srow = tid >> 3, sc8 = (tid & 7) * 8;
    f32x4 acc[4][4] = {};

    for (int kk = 0; kk < 512; kk += 64) {
        #pragma unroll
        for (int r = 0; r < 4; ++r) {
            int row = r * 32 + srow;
            GLD16(BT + (size_t)(n0 + row) * 512 + kk + sc8, &Bs[row * 64 + sc8]);
            const float* ap = A + (size_t)(m0 + row) * 512 + kk + sc8;
            f32x4 v0 = *(const f32x4*)(ap);
            f32x4 v1 = *(const f32x4*)(ap + 4);
            u16x8 hv;
            hv[0]=f2h(v0[0]); hv[1]=f2h(v0[1]); hv[2]=f2h(v0[2]); hv[3]=f2h(v0[3]);
            hv[4]=f2h(v1[0]); hv[5]=f2h(v1[1]); hv[6]=f2h(v1[2]); hv[7]=f2h(v1[3]);
            *(u16x8*)&As[row * 64 + sc8] = hv;
        }
        __syncthreads();
        #pragma unroll
        for (int kt = 0; kt < 2; ++kt) {
            f16x8 af[4], bfr[4];
            #pragma unroll
            for (int mt = 0; mt < 4; ++mt)
                af[mt] = *(const f16x8*)&As[(wr*64 + mt*16 + al) * 64 + kt*32 + g*8];
            #pragma unroll
            for (int nt = 0; nt < 4; ++nt)
                bfr[nt] = *(const f16x8*)&Bs[(wc*64 + nt*16 + al) * 64 + kt*32 + g*8];
            #pragma unroll
            for (int mt = 0; mt < 4; ++mt)
                #pragma unroll
                for (int nt = 0; nt < 4; ++nt)
                    acc[mt][nt] = __builtin_amdgcn_mfma_f32_16x16x32_f16(af[mt], bfr[nt], acc[mt][nt], 0, 0, 0);
        }
        __syncthreads();
    }
    #pragma unroll
    for (int nt = 0; nt < 4; ++nt) {
        int col = n0 + wc*64 + nt*16 + al;
        float bv = bias[col];
        #pragma unroll
        for (int mt = 0; mt < 4; ++mt)
            #pragma unroll
            for (int rg = 0; rg < 4; ++rg) {
                size_t row = (size_t)(m0 + wr*64 + mt*16 + g*4 + rg);
                outp[row * 512 + col] = f2h((acc[mt][nt][rg] + bv) * scale);
            }
    }
}

// ---------------- V GEMM: BK=32, A fp32 reg-staged -> fp16, B via gld_lds
// Output: V^T per head, layout [window][h][d(32)][k(64)], fp16
__global__ __launch_bounds__(256, 4) void gemm_v(
    const float* __restrict__ A, const u16* __restrict__ BT,
    const float* __restrict__ bias, u16* __restrict__ outp)
{
    __shared__ u16 As[128*32], Bs[128*32];
    const int tid = threadIdx.x;
    const int l = tid & 63, w = tid >> 6;
    const int al = l & 15, g = l >> 4;
    const int wr = w >> 1, wc = w & 1;
    const int wg = swz4096(blockIdx.x);
    const int n0 = (wg & 3) * 128, m0 = (wg >> 2) * 128;
    const int srow = tid >> 2, sc8 = (tid & 3) * 8;
    f32x4 acc[4][4] = {};

    for (int kk = 0; kk < 512; kk += 32) {
        #pragma unroll
        for (int r = 0; r < 2; ++r) {
            int row = r * 64 + srow;
            GLD16(BT + (size_t)(n0 + row) * 512 + kk + sc8, &Bs[row * 32 + sc8]);
            const float* ap = A + (size_t)(m0 + row) * 512 + kk + sc8;
            f32x4 v0 = *(const f32x4*)(ap);
            f32x4 v1 = *(const f32x4*)(ap + 4);
            u16x8 hv;
            hv[0]=f2h(v0[0]); hv[1]=f2h(v0[1]); hv[2]=f2h(v0[2]); hv[3]=f2h(v0[3]);
            hv[4]=f2h(v1[0]); hv[5]=f2h(v1[1]); hv[6]=f2h(v1[2]); hv[7]=f2h(v1[3]);
            *(u16x8*)&As[row * 32 + sc8] = hv;
        }
        __syncthreads();
        {
            f16x8 af[4], bfr[4];
            #pragma unroll
            for (int mt = 0; mt < 4; ++mt)
                af[mt] = *(const f16x8*)&As[(wr*64 + mt*16 + al) * 32 + g*8];
            #pragma unroll
            for (int nt = 0; nt < 4; ++nt)
                bfr[nt] = *(const f16x8*)&Bs[(wc*64 + nt*16 + al) * 32 + g*8];
            #pragma unroll
            for (int mt = 0; mt < 4; ++mt)
                #pragma unroll
                for (int nt = 0; nt < 4; ++nt)
                    acc[mt][nt] = __builtin_amdgcn_mfma_f32_16x16x32_f16(af[mt], bfr[nt], acc[mt][nt], 0, 0, 0);
        }
        __syncthreads();
    }
    #pragma unroll
    for (int nt = 0; nt < 4; ++nt) {
        int col = n0 + wc*64 + nt*16 + al;
        int hh_ = col >> 5, d = col & 31;
        float bv = bias[col];
        #pragma unroll
        for (int mt = 0; mt < 4; ++mt) {
            int row0 = m0 + wr*64 + mt*16 + g*4;
            int window = row0 >> 6, k0 = row0 & 63;
            size_t off = ((size_t)window << 15) + (hh_ << 11) + (d << 6) + k0;
            u16x4 hv;
            #pragma unroll
            for (int rg = 0; rg < 4; ++rg)
                hv[rg] = f2h(acc[mt][nt][rg] + bv);
            *(u16x4*)(outp + off) = hv;
        }
    }
}

// ---------------- proj GEMM: BK=32, A (fp16 O) + B via global_load_lds, fp32 out
__global__ __launch_bounds__(256, 4) void gemm_proj(
    const u16* __restrict__ A1, const u16* __restrict__ BT,
    const float* __restrict__ bias, float* __restrict__ outp)
{
    __shared__ u16 As[128*32], Bs[128*32];
    const int tid = threadIdx.x;
    const int l = tid & 63, w = tid >> 6;
    const int al = l & 15, g = l >> 4;
    const int wr = w >> 1, wc = w & 1;
    const int wg = swz4096(blockIdx.x);
    const int n0 = (wg & 3) * 128, m0 = (wg >> 2) * 128;
    const int srow = tid >> 2, sc8 = (tid & 3) * 8;
    f32x4 acc[4][4] = {};

    for (int kk = 0; kk < 512; kk += 32) {
        #pragma unroll
        for (int r = 0; r < 2; ++r) {
            int row = r * 64 + srow;
            size_t aoff = (size_t)(m0 + row) * 512 + kk + sc8;
            size_t boff = (size_t)(n0 + row) * 512 + kk + sc8;
            int loff = row * 32 + sc8;
            GLD16(A1 + aoff, &As[loff]);
            GLD16(BT + boff, &Bs[loff]);
        }
        __syncthreads();
        {
            f16x8 af[4], bfr[4];
            #pragma unroll
            for (int mt = 0; mt < 4; ++mt)
                af[mt] = *(const f16x8*)&As[(wr*64 + mt*16 + al) * 32 + g*8];
            #pragma unroll
            for (int nt = 0; nt < 4; ++nt)
                bfr[nt] = *(const f16x8*)&Bs[(wc*64 + nt*16 + al) * 32 + g*8];
            #pragma unroll
            for (int mt = 0; mt < 4; ++mt)
                #pragma unroll
                for (int nt = 0; nt < 4; ++nt)
                    acc[mt][nt] = __builtin_amdgcn_mfma_f32_16x16x32_f16(af[mt], bfr[nt], acc[mt][nt], 0, 0, 0);
        }
        __syncthreads();
    }
    #pragma unroll
    for (int nt = 0; nt < 4; ++nt) {
        int col = n0 + wc*64 + nt*16 + al;
        float bv = bias[col];
        #pragma unroll
        for (int mt = 0; mt < 4; ++mt)
            #pragma unroll
            for (int rg = 0; rg < 4; ++rg) {
                size_t row = (size_t)(m0 + wr*64 + mt*16 + g*4 + rg);
                outp[row * 512 + col] = acc[mt][nt][rg] + bv;
            }
    }
}

// ---------------- fused window attention (fp16, phase-grouped) ----------------
// grid (2048, 4). Window remap: XCD x only handles windows with (b&63)>>3 == x,
// so each XCD's cmb slice (8 wmods * 256KB = 2MB) stays L2-resident.
__global__ __launch_bounds__(256) void attn64(
    const u16* __restrict__ Q, const u16* __restrict__ Kb,
    const u16* __restrict__ Vth,
    const float* __restrict__ cmb,
    u16* __restrict__ Oout)
{
    __shared__ u16 Ph[4][64 * 72];
    const int bid = blockIdx.x;
    const int xcd = bid & 7, idx = bid >> 3;
    const int b = ((idx >> 3) << 6) | (xcd << 3) | (idx & 7);   // bijective
    const int tid = threadIdx.x;
    const int l = tid & 63, w = tid >> 6;
    const int al = l & 15, g = l >> 4;
    const size_t rbase = (size_t)b * 64;
    const int h = blockIdx.y * 4 + w;
    const int co = h * 32;

    // V^T fragments first (latency hidden under QK+softmax)
    const u16* vth = Vth + ((size_t)b << 15) + (h << 11);
    f16x8 vhf[2][2];
    #pragma unroll
    for (int kt = 0; kt < 2; ++kt)
        #pragma unroll
        for (int dt = 0; dt < 2; ++dt) {
            int voff = ((dt*16 + al) << 6) + kt*32 + g*8;
            vhf[kt][dt] = *(const f16x8*)(vth + voff);
        }

    f16x8 qf[4], kf[4];
    #pragma unroll
    for (int t = 0; t < 4; ++t) {
        qf[t] = *(const f16x8*)(Q  + (rbase + t*16 + al) * 512 + co + g*8);
        kf[t] = *(const f16x8*)(Kb + (rbase + t*16 + al) * 512 + co + g*8);
    }
    f32x4 s[4][4] = {};
    #pragma unroll
    for (int mt = 0; mt < 4; ++mt)
        #pragma unroll
        for (int nt = 0; nt < 4; ++nt)
            s[mt][nt] = __builtin_amdgcn_mfma_f32_16x16x32_f16(qf[mt], kf[nt], s[mt][nt], 0, 0, 0);

    const float* cp = cmb + ((((size_t)(b & 63)) * 16 + h) << 12);
    #pragma unroll
    for (int mt = 0; mt < 4; ++mt)
        #pragma unroll
        for (int nt = 0; nt < 4; ++nt) {
            f32x4 c4 = *(const f32x4*)(cp + ((nt*16 + al) << 6) + mt*16 + g*4);
            #pragma unroll
            for (int rg = 0; rg < 4; ++rg) s[mt][nt][rg] += c4[rg];
        }

    // ---- softmax for all 4 mt (registers only), then one LDS phase ----
    f32x4 sm[4];
    #pragma unroll
    for (int mt = 0; mt < 4; ++mt) {
        f32x4 m4 = s[mt][0];
        #pragma unroll
        for (int nt = 1; nt < 4; ++nt)
            #pragma unroll
            for (int c = 0; c < 4; ++c) m4[c] = fmaxf(m4[c], s[mt][nt][c]);
        #pragma unroll
        for (int d = 1; d < 16; d <<= 1)
            #pragma unroll
            for (int c = 0; c < 4; ++c) m4[c] = fmaxf(m4[c], shflx(m4[c], d));
        #pragma unroll
        for (int nt = 0; nt < 4; ++nt)
            #pragma unroll
            for (int rg = 0; rg < 4; ++rg)
                s[mt][nt][rg] = exp2f((s[mt][nt][rg] - m4[rg]) * LOG2E);
        f32x4 s4 = s[mt][0];
        #pragma unroll
        for (int nt = 1; nt < 4; ++nt) s4 += s[mt][nt];
        #pragma unroll
        for (int d = 1; d < 16; d <<= 1)
            #pragma unroll
            for (int c = 0; c < 4; ++c) s4[c] += shflx(s4[c], d);
        sm[mt] = s4;
    }

    // write all of P (per-wave buffer; same-wave read below, no barrier)
    #pragma unroll
    for (int mt = 0; mt < 4; ++mt)
        #pragma unroll
        for (int nt = 0; nt < 4; ++nt)
            #pragma unroll
            for (int rg = 0; rg < 4; ++rg) {
                int off = (mt*16 + g*4 + rg) * 72 + nt*16 + al;
                Ph[w][off] = f2h(s[mt][nt][rg]);
            }

    // ---- PV for all mt, back-to-back MFMAs ----
    #pragma unroll
    for (int mt = 0; mt < 4; ++mt) {
        f16x8 pah[2];
        #pragma unroll
        for (int kt = 0; kt < 2; ++kt)
            pah[kt] = *(const f16x8*)&Ph[w][(mt*16 + al) * 72 + kt*32 + g*8];
        f32x4 o[2] = {};
        #pragma unroll
        for (int dt = 0; dt < 2; ++dt)
            #pragma unroll
            for (int kt = 0; kt < 2; ++kt)
                o[dt] = __builtin_amdgcn_mfma_f32_16x16x32_f16(pah[kt], vhf[kt][dt], o[dt], 0, 0, 0);
        #pragma unroll
        for (int dt = 0; dt < 2; ++dt)
            #pragma unroll
            for (int rg = 0; rg < 4; ++rg) {
                float inv = __builtin_amdgcn_rcpf(sm[mt][rg]);
                float v = o[dt][rg] * inv;
                size_t off = (rbase + mt*16 + g*4 + rg) * 512 + co + dt*16 + al;
                Oout[off] = f2h(v);
            }
    }
}

// ---------------- launch ----------------
extern "C" void kernel_launch(void* const* d_in, const int* in_sizes, int n_in,
                              void* d_out, int out_size, void* d_ws, size_t ws_size,
                              hipStream_t stream)
{
    const float* x      = (const float*)d_in[0];
    const float* y      = (const float*)d_in[1];
    const float* mask   = (const float*)d_in[2];
    const float* W_q    = (const float*)d_in[3];
    const float* b_q    = (const float*)d_in[4];
    const float* W_kv   = (const float*)d_in[5];
    const float* b_kv   = (const float*)d_in[6];
    const float* W_proj = (const float*)d_in[7];
    const float* b_proj = (const float*)d_in[8];
    const float* table  = (const float*)d_in[9];

    char* ws = (char*)d_ws;
    const size_t SEG = (size_t)MROWS * 512 * sizeof(u16);   // 128 MB
    u16* Qs     = (u16*)(ws);              // aliased by O after attention
    u16* Ks     = (u16*)(ws + SEG);
    u16* Vth    = (u16*)(ws + 2 * SEG);    // V^T [win][h][d][k], fp16
    u16* wqT    = (u16*)(ws + 3 * SEG);
    u16* wkvKT  = wqT    + 512 * 512;
    u16* wkvVT  = wkvKT  + 512 * 512;
    u16* wprT   = wkvVT  + 512 * 512;
    float* cmb  = (float*)(wprT + 512 * 512);   // 64*16*4096*4B = 16 MB

    wt_f16<<<1024, 256, 0, stream>>>(W_q, 512, 0, wqT, 512);
    wt_f16<<<1024, 256, 0, stream>>>(W_kv, 1024, 0, wkvKT, 512);
    wt_f16<<<1024, 256, 0, stream>>>(W_kv, 1024, 512, wkvVT, 512);
    wt_f16<<<1024, 256, 0, stream>>>(W_proj, 512, 0, wprT, 512);
    cmb_pre<<<dim3(64, 16), 256, 0, stream>>>(table, mask, cmb);

    gemm_qk<<<4096, 256, 0, stream>>>(x, wqT, b_q, Qs, QSCALE);
    gemm_qk<<<4096, 256, 0, stream>>>(y, wkvKT, b_kv, Ks, 1.0f);
    gemm_v<<<4096, 256, 0, stream>>>(y, wkvVT, b_kv + 512, Vth);
    attn64<<<dim3(2048, 4), 256, 0, stream>>>(Qs, Ks, Vth, cmb, Qs);
    gemm_proj<<<4096, 256, 0, stream>>>(Qs, wprT, b_proj, (float*)d_out);
}

// Round 10
// 782.662 us; speedup vs baseline: 1.8996x; 1.0595x over previous
//
#include <hip/hip_runtime.h>
#include <stdint.h>

#define MROWS 131072                     // 2048 windows * 64 tokens
#define LOG2E 1.44269504088896340736f
#define QSCALE 0.17677669529663688110f   // 32^-0.5

typedef _Float16 f16x8 __attribute__((ext_vector_type(8)));
typedef float f32x4 __attribute__((ext_vector_type(4)));
typedef unsigned short u16;
typedef u16 u16x4 __attribute__((ext_vector_type(4)));
typedef u16 u16x8 __attribute__((ext_vector_type(8)));

#define GLD16(gp, lp) __builtin_amdgcn_global_load_lds( \
    (const __attribute__((address_space(1))) void*)(gp), \
    (__attribute__((address_space(3))) void*)(lp), 16, 0, 0)

static __device__ __forceinline__ u16 f2h(float f) {
    _Float16 h = (_Float16)f;             // RNE
    return __builtin_bit_cast(unsigned short, h);
}
static __device__ __forceinline__ float shflx(float v, int m) {
    return __shfl_xor(v, m, 64);
}
// bijective XCD swizzle: 4096 wgs, 8 XCDs, 512-wg contiguous chunk per XCD
static __device__ __forceinline__ int swz4096(int bid) {
    return (bid & 7) * 512 + (bid >> 3);
}

// ---------------- setup kernels ----------------
__global__ void wt_f16(const float* __restrict__ W, int ldW, int colOff,
                       u16* __restrict__ WT, int K) {
    int idx = blockIdx.x * 256 + threadIdx.x;
    int n = idx / K, k = idx - n * K;
    WT[idx] = f2h(W[(size_t)k * ldW + colOff + n]);
}
// combined (rel-pos bias + shift mask), stored TRANSPOSED: cmb[wmod][h][j][i]
__global__ void cmb_pre(const float* __restrict__ table, const float* __restrict__ mask,
                        float* __restrict__ cmb) {
    int wmod = blockIdx.x, h = blockIdx.y;
    float* outp = cmb + (((size_t)wmod * 16 + h) << 12);
    const float* mp = mask + ((size_t)wmod << 12);
    for (int e = threadIdx.x; e < 4096; e += 256) {
        int j = e >> 6, i = e & 63;
        int idx = ((i >> 3) - (j >> 3) + 7) * 15 + ((i & 7) - (j & 7) + 7);
        outp[e] = table[idx * 16 + h] + mp[i * 64 + j];
    }
}

// ---------------- Q/K GEMM: BK=32, A fp32 reg-staged -> fp16 LDS, B via gld_lds
__global__ __launch_bounds__(256, 4) void gemm_qk(
    const float* __restrict__ A, const u16* __restrict__ BT,
    const float* __restrict__ bias, u16* __restrict__ outp, float scale)
{
    __shared__ u16 As[128 * 32];
    __shared__ u16 Bs[128 * 32];
    const int tid = threadIdx.x;
    const int l = tid & 63, w = tid >> 6;
    const int al = l & 15, g = l >> 4;
    const int wr = w >> 1, wc = w & 1;
    const int wg = swz4096(blockIdx.x);
    const int n0 = (wg & 3) * 128, m0 = (wg >> 2) * 128;
    const int srow = tid >> 2, sc8 = (tid & 3) * 8;
    f32x4 acc[4][4] = {};

    for (int kk = 0; kk < 512; kk += 32) {
        #pragma unroll
        for (int r = 0; r < 2; ++r) {
            int row = r * 64 + srow;
            GLD16(BT + (size_t)(n0 + row) * 512 + kk + sc8, &Bs[row * 32 + sc8]);
            const float* ap = A + (size_t)(m0 + row) * 512 + kk + sc8;
            f32x4 v0 = *(const f32x4*)(ap);
            f32x4 v1 = *(const f32x4*)(ap + 4);
            u16x8 hv;
            hv[0]=f2h(v0[0]); hv[1]=f2h(v0[1]); hv[2]=f2h(v0[2]); hv[3]=f2h(v0[3]);
            hv[4]=f2h(v1[0]); hv[5]=f2h(v1[1]); hv[6]=f2h(v1[2]); hv[7]=f2h(v1[3]);
            *(u16x8*)&As[row * 32 + sc8] = hv;
        }
        __syncthreads();
        {
            f16x8 af[4], bfr[4];
            #pragma unroll
            for (int mt = 0; mt < 4; ++mt)
                af[mt] = *(const f16x8*)&As[(wr*64 + mt*16 + al) * 32 + g*8];
            #pragma unroll
            for (int nt = 0; nt < 4; ++nt)
                bfr[nt] = *(const f16x8*)&Bs[(wc*64 + nt*16 + al) * 32 + g*8];
            #pragma unroll
            for (int mt = 0; mt < 4; ++mt)
                #pragma unroll
                for (int nt = 0; nt < 4; ++nt)
                    acc[mt][nt] = __builtin_amdgcn_mfma_f32_16x16x32_f16(af[mt], bfr[nt], acc[mt][nt], 0, 0, 0);
        }
        __syncthreads();
    }
    #pragma unroll
    for (int nt = 0; nt < 4; ++nt) {
        int col = n0 + wc*64 + nt*16 + al;
        float bv = bias[col];
        #pragma unroll
        for (int mt = 0; mt < 4; ++mt)
            #pragma unroll
            for (int rg = 0; rg < 4; ++rg) {
                size_t row = (size_t)(m0 + wr*64 + mt*16 + g*4 + rg);
                outp[row * 512 + col] = f2h((acc[mt][nt][rg] + bv) * scale);
            }
    }
}

// ---------------- V GEMM: BK=32, A fp32 reg-staged -> fp16, B via gld_lds
// Output: V^T per head, layout [window][h][d(32)][k(64)], fp16
__global__ __launch_bounds__(256, 4) void gemm_v(
    const float* __restrict__ A, const u16* __restrict__ BT,
    const float* __restrict__ bias, u16* __restrict__ outp)
{
    __shared__ u16 As[128*32], Bs[128*32];
    const int tid = threadIdx.x;
    const int l = tid & 63, w = tid >> 6;
    const int al = l & 15, g = l >> 4;
    const int wr = w >> 1, wc = w & 1;
    const int wg = swz4096(blockIdx.x);
    const int n0 = (wg & 3) * 128, m0 = (wg >> 2) * 128;
    const int srow = tid >> 2, sc8 = (tid & 3) * 8;
    f32x4 acc[4][4] = {};

    for (int kk = 0; kk < 512; kk += 32) {
        #pragma unroll
        for (int r = 0; r < 2; ++r) {
            int row = r * 64 + srow;
            GLD16(BT + (size_t)(n0 + row) * 512 + kk + sc8, &Bs[row * 32 + sc8]);
            const float* ap = A + (size_t)(m0 + row) * 512 + kk + sc8;
            f32x4 v0 = *(const f32x4*)(ap);
            f32x4 v1 = *(const f32x4*)(ap + 4);
            u16x8 hv;
            hv[0]=f2h(v0[0]); hv[1]=f2h(v0[1]); hv[2]=f2h(v0[2]); hv[3]=f2h(v0[3]);
            hv[4]=f2h(v1[0]); hv[5]=f2h(v1[1]); hv[6]=f2h(v1[2]); hv[7]=f2h(v1[3]);
            *(u16x8*)&As[row * 32 + sc8] = hv;
        }
        __syncthreads();
        {
            f16x8 af[4], bfr[4];
            #pragma unroll
            for (int mt = 0; mt < 4; ++mt)
                af[mt] = *(const f16x8*)&As[(wr*64 + mt*16 + al) * 32 + g*8];
            #pragma unroll
            for (int nt = 0; nt < 4; ++nt)
                bfr[nt] = *(const f16x8*)&Bs[(wc*64 + nt*16 + al) * 32 + g*8];
            #pragma unroll
            for (int mt = 0; mt < 4; ++mt)
                #pragma unroll
                for (int nt = 0; nt < 4; ++nt)
                    acc[mt][nt] = __builtin_amdgcn_mfma_f32_16x16x32_f16(af[mt], bfr[nt], acc[mt][nt], 0, 0, 0);
        }
        __syncthreads();
    }
    #pragma unroll
    for (int nt = 0; nt < 4; ++nt) {
        int col = n0 + wc*64 + nt*16 + al;
        int hh_ = col >> 5, d = col & 31;
        float bv = bias[col];
        #pragma unroll
        for (int mt = 0; mt < 4; ++mt) {
            int row0 = m0 + wr*64 + mt*16 + g*4;
            int window = row0 >> 6, k0 = row0 & 63;
            size_t off = ((size_t)window << 15) + (hh_ << 11) + (d << 6) + k0;
            u16x4 hv;
            #pragma unroll
            for (int rg = 0; rg < 4; ++rg)
                hv[rg] = f2h(acc[mt][nt][rg] + bv);
            *(u16x4*)(outp + off) = hv;
        }
    }
}

// ---------------- proj GEMM: BK=32, A (fp16 O) + B via global_load_lds, fp32 out
__global__ __launch_bounds__(256, 4) void gemm_proj(
    const u16* __restrict__ A1, const u16* __restrict__ BT,
    const float* __restrict__ bias, float* __restrict__ outp)
{
    __shared__ u16 As[128*32], Bs[128*32];
    const int tid = threadIdx.x;
    const int l = tid & 63, w = tid >> 6;
    const int al = l & 15, g = l >> 4;
    const int wr = w >> 1, wc = w & 1;
    const int wg = swz4096(blockIdx.x);
    const int n0 = (wg & 3) * 128, m0 = (wg >> 2) * 128;
    const int srow = tid >> 2, sc8 = (tid & 3) * 8;
    f32x4 acc[4][4] = {};

    for (int kk = 0; kk < 512; kk += 32) {
        #pragma unroll
        for (int r = 0; r < 2; ++r) {
            int row = r * 64 + srow;
            size_t aoff = (size_t)(m0 + row) * 512 + kk + sc8;
            size_t boff = (size_t)(n0 + row) * 512 + kk + sc8;
            int loff = row * 32 + sc8;
            GLD16(A1 + aoff, &As[loff]);
            GLD16(BT + boff, &Bs[loff]);
        }
        __syncthreads();
        {
            f16x8 af[4], bfr[4];
            #pragma unroll
            for (int mt = 0; mt < 4; ++mt)
                af[mt] = *(const f16x8*)&As[(wr*64 + mt*16 + al) * 32 + g*8];
            #pragma unroll
            for (int nt = 0; nt < 4; ++nt)
                bfr[nt] = *(const f16x8*)&Bs[(wc*64 + nt*16 + al) * 32 + g*8];
            #pragma unroll
            for (int mt = 0; mt < 4; ++mt)
                #pragma unroll
                for (int nt = 0; nt < 4; ++nt)
                    acc[mt][nt] = __builtin_amdgcn_mfma_f32_16x16x32_f16(af[mt], bfr[nt], acc[mt][nt], 0, 0, 0);
        }
        __syncthreads();
    }
    #pragma unroll
    for (int nt = 0; nt < 4; ++nt) {
        int col = n0 + wc*64 + nt*16 + al;
        float bv = bias[col];
        #pragma unroll
        for (int mt = 0; mt < 4; ++mt)
            #pragma unroll
            for (int rg = 0; rg < 4; ++rg) {
                size_t row = (size_t)(m0 + wr*64 + mt*16 + g*4 + rg);
                outp[row * 512 + col] = acc[mt][nt][rg] + bv;
            }
    }
}

// ---------------- fused window attention (fp16, phase-grouped) ----------------
// grid (2048, 4). Window remap: XCD x only handles windows with (b&63)>>3 == x,
// so each XCD's cmb slice (8 wmods * 256KB = 2MB) stays L2-resident.
__global__ __launch_bounds__(256) void attn64(
    const u16* __restrict__ Q, const u16* __restrict__ Kb,
    const u16* __restrict__ Vth,
    const float* __restrict__ cmb,
    u16* __restrict__ Oout)
{
    __shared__ u16 Ph[4][64 * 72];
    const int bid = blockIdx.x;
    const int xcd = bid & 7, idx = bid >> 3;
    const int b = ((idx >> 3) << 6) | (xcd << 3) | (idx & 7);   // bijective
    const int tid = threadIdx.x;
    const int l = tid & 63, w = tid >> 6;
    const int al = l & 15, g = l >> 4;
    const size_t rbase = (size_t)b * 64;
    const int h = blockIdx.y * 4 + w;
    const int co = h * 32;

    // V^T fragments first (latency hidden under QK+softmax)
    const u16* vth = Vth + ((size_t)b << 15) + (h << 11);
    f16x8 vhf[2][2];
    #pragma unroll
    for (int kt = 0; kt < 2; ++kt)
        #pragma unroll
        for (int dt = 0; dt < 2; ++dt) {
            int voff = ((dt*16 + al) << 6) + kt*32 + g*8;
            vhf[kt][dt] = *(const f16x8*)(vth + voff);
        }

    f16x8 qf[4], kf[4];
    #pragma unroll
    for (int t = 0; t < 4; ++t) {
        qf[t] = *(const f16x8*)(Q  + (rbase + t*16 + al) * 512 + co + g*8);
        kf[t] = *(const f16x8*)(Kb + (rbase + t*16 + al) * 512 + co + g*8);
    }
    f32x4 s[4][4] = {};
    #pragma unroll
    for (int mt = 0; mt < 4; ++mt)
        #pragma unroll
        for (int nt = 0; nt < 4; ++nt)
            s[mt][nt] = __builtin_amdgcn_mfma_f32_16x16x32_f16(qf[mt], kf[nt], s[mt][nt], 0, 0, 0);

    const float* cp = cmb + ((((size_t)(b & 63)) * 16 + h) << 12);
    #pragma unroll
    for (int mt = 0; mt < 4; ++mt)
        #pragma unroll
        for (int nt = 0; nt < 4; ++nt) {
            f32x4 c4 = *(const f32x4*)(cp + ((nt*16 + al) << 6) + mt*16 + g*4);
            #pragma unroll
            for (int rg = 0; rg < 4; ++rg) s[mt][nt][rg] += c4[rg];
        }

    // ---- softmax for all 4 mt (registers only), then one LDS phase ----
    f32x4 sm[4];
    #pragma unroll
    for (int mt = 0; mt < 4; ++mt) {
        f32x4 m4 = s[mt][0];
        #pragma unroll
        for (int nt = 1; nt < 4; ++nt)
            #pragma unroll
            for (int c = 0; c < 4; ++c) m4[c] = fmaxf(m4[c], s[mt][nt][c]);
        #pragma unroll
        for (int d = 1; d < 16; d <<= 1)
            #pragma unroll
            for (int c = 0; c < 4; ++c) m4[c] = fmaxf(m4[c], shflx(m4[c], d));
        #pragma unroll
        for (int nt = 0; nt < 4; ++nt)
            #pragma unroll
            for (int rg = 0; rg < 4; ++rg)
                s[mt][nt][rg] = exp2f((s[mt][nt][rg] - m4[rg]) * LOG2E);
        f32x4 s4 = s[mt][0];
        #pragma unroll
        for (int nt = 1; nt < 4; ++nt) s4 += s[mt][nt];
        #pragma unroll
        for (int d = 1; d < 16; d <<= 1)
            #pragma unroll
            for (int c = 0; c < 4; ++c) s4[c] += shflx(s4[c], d);
        sm[mt] = s4;
    }

    // write all of P (per-wave buffer; same-wave read below, no barrier)
    #pragma unroll
    for (int mt = 0; mt < 4; ++mt)
        #pragma unroll
        for (int nt = 0; nt < 4; ++nt)
            #pragma unroll
            for (int rg = 0; rg < 4; ++rg) {
                int off = (mt*16 + g*4 + rg) * 72 + nt*16 + al;
                Ph[w][off] = f2h(s[mt][nt][rg]);
            }

    // ---- PV for all mt, back-to-back MFMAs ----
    #pragma unroll
    for (int mt = 0; mt < 4; ++mt) {
        f16x8 pah[2];
        #pragma unroll
        for (int kt = 0; kt < 2; ++kt)
            pah[kt] = *(const f16x8*)&Ph[w][(mt*16 + al) * 72 + kt*32 + g*8];
        f32x4 o[2] = {};
        #pragma unroll
        for (int dt = 0; dt < 2; ++dt)
            #pragma unroll
            for (int kt = 0; kt < 2; ++kt)
                o[dt] = __builtin_amdgcn_mfma_f32_16x16x32_f16(pah[kt], vhf[kt][dt], o[dt], 0, 0, 0);
        #pragma unroll
        for (int dt = 0; dt < 2; ++dt)
            #pragma unroll
            for (int rg = 0; rg < 4; ++rg) {
                float inv = __builtin_amdgcn_rcpf(sm[mt][rg]);
                float v = o[dt][rg] * inv;
                size_t off = (rbase + mt*16 + g*4 + rg) * 512 + co + dt*16 + al;
                Oout[off] = f2h(v);
            }
    }
}

// ---------------- launch ----------------
extern "C" void kernel_launch(void* const* d_in, const int* in_sizes, int n_in,
                              void* d_out, int out_size, void* d_ws, size_t ws_size,
                              hipStream_t stream)
{
    const float* x      = (const float*)d_in[0];
    const float* y      = (const float*)d_in[1];
    const float* mask   = (const float*)d_in[2];
    const float* W_q    = (const float*)d_in[3];
    const float* b_q    = (const float*)d_in[4];
    const float* W_kv   = (const float*)d_in[5];
    const float* b_kv   = (const float*)d_in[6];
    const float* W_proj = (const float*)d_in[7];
    const float* b_proj = (const float*)d_in[8];
    const float* table  = (const float*)d_in[9];

    char* ws = (char*)d_ws;
    const size_t SEG = (size_t)MROWS * 512 * sizeof(u16);   // 128 MB
    u16* Qs     = (u16*)(ws);              // aliased by O after attention
    u16* Ks     = (u16*)(ws + SEG);
    u16* Vth    = (u16*)(ws + 2 * SEG);    // V^T [win][h][d][k], fp16
    u16* wqT    = (u16*)(ws + 3 * SEG);
    u16* wkvKT  = wqT    + 512 * 512;
    u16* wkvVT  = wkvKT  + 512 * 512;
    u16* wprT   = wkvVT  + 512 * 512;
    float* cmb  = (float*)(wprT + 512 * 512);   // 64*16*4096*4B = 16 MB

    wt_f16<<<1024, 256, 0, stream>>>(W_q, 512, 0, wqT, 512);
    wt_f16<<<1024, 256, 0, stream>>>(W_kv, 1024, 0, wkvKT, 512);
    wt_f16<<<1024, 256, 0, stream>>>(W_kv, 1024, 512, wkvVT, 512);
    wt_f16<<<1024, 256, 0, stream>>>(W_proj, 512, 0, wprT, 512);
    cmb_pre<<<dim3(64, 16), 256, 0, stream>>>(table, mask, cmb);

    gemm_qk<<<4096, 256, 0, stream>>>(x, wqT, b_q, Qs, QSCALE);
    gemm_qk<<<4096, 256, 0, stream>>>(y, wkvKT, b_kv, Ks, 1.0f);
    gemm_v<<<4096, 256, 0, stream>>>(y, wkvVT, b_kv + 512, Vth);
    attn64<<<dim3(2048, 4), 256, 0, stream>>>(Qs, Ks, Vth, cmb, Qs);
    gemm_proj<<<4096, 256, 0, stream>>>(Qs, wprT, b_proj, (float*)d_out);
}

// Round 11
// 780.256 us; speedup vs baseline: 1.9055x; 1.0031x over previous
//
#include <hip/hip_runtime.h>
#include <stdint.h>

#define MROWS 131072                     // 2048 windows * 64 tokens
#define LOG2E 1.44269504088896340736f
#define QSCALE 0.17677669529663688110f   // 32^-0.5

typedef _Float16 f16x8 __attribute__((ext_vector_type(8)));
typedef float f32x4 __attribute__((ext_vector_type(4)));
typedef unsigned short u16;
typedef u16 u16x4 __attribute__((ext_vector_type(4)));
typedef u16 u16x8 __attribute__((ext_vector_type(8)));

#define GLD16(gp, lp) __builtin_amdgcn_global_load_lds( \
    (const __attribute__((address_space(1))) void*)(gp), \
    (__attribute__((address_space(3))) void*)(lp), 16, 0, 0)

static __device__ __forceinline__ u16 f2h(float f) {
    _Float16 h = (_Float16)f;             // RNE
    return __builtin_bit_cast(unsigned short, h);
}
static __device__ __forceinline__ float shflx(float v, int m) {
    return __shfl_xor(v, m, 64);
}
// bijective XCD swizzle: 4096 wgs, 8 XCDs, 512-wg contiguous chunk per XCD
static __device__ __forceinline__ int swz4096(int bid) {
    return (bid & 7) * 512 + (bid >> 3);
}

// ---------------- setup kernels ----------------
__global__ void wt_f16(const float* __restrict__ W, int ldW, int colOff,
                       u16* __restrict__ WT, int K) {
    int idx = blockIdx.x * 256 + threadIdx.x;
    int n = idx / K, k = idx - n * K;
    WT[idx] = f2h(W[(size_t)k * ldW + colOff + n]);
}
// combined (rel-pos bias + shift mask), stored TRANSPOSED: cmb[wmod][h][j][i]
__global__ void cmb_pre(const float* __restrict__ table, const float* __restrict__ mask,
                        float* __restrict__ cmb) {
    int wmod = blockIdx.x, h = blockIdx.y;
    float* outp = cmb + (((size_t)wmod * 16 + h) << 12);
    const float* mp = mask + ((size_t)wmod << 12);
    for (int e = threadIdx.x; e < 4096; e += 256) {
        int j = e >> 6, i = e & 63;
        int idx = ((i >> 3) - (j >> 3) + 7) * 15 + ((i & 7) - (j & 7) + 7);
        outp[e] = table[idx * 16 + h] + mp[i * 64 + j];
    }
}

// ---------------- Q/K GEMM: BK=32, dbuf 1-barrier pipeline
// A fp32 reg-prefetch -> cvt fp16 -> LDS; B via global_load_lds (issued 1 phase ahead)
__global__ __launch_bounds__(256, 4) void gemm_qk(
    const float* __restrict__ A, const u16* __restrict__ BT,
    const float* __restrict__ bias, u16* __restrict__ outp, float scale)
{
    __shared__ u16 As[2][128 * 32];
    __shared__ u16 Bs[2][128 * 32];
    const int tid = threadIdx.x;
    const int l = tid & 63, w = tid >> 6;
    const int al = l & 15, g = l >> 4;
    const int wr = w >> 1, wc = w & 1;
    const int wg = swz4096(blockIdx.x);
    const int n0 = (wg & 3) * 128, m0 = (wg >> 2) * 128;
    const int srow = tid >> 2, sc8 = (tid & 3) * 8;
    const float* asrc0 = A  + (size_t)(m0 + srow) * 512 + sc8;
    const float* asrc1 = A  + (size_t)(m0 + 64 + srow) * 512 + sc8;
    const u16*   bsrc0 = BT + (size_t)(n0 + srow) * 512 + sc8;
    const u16*   bsrc1 = BT + (size_t)(n0 + 64 + srow) * 512 + sc8;
    const int lo0 = srow * 32 + sc8, lo1 = (64 + srow) * 32 + sc8;
    f32x4 acc[4][4] = {};

    // prologue: loads for iter 0 into buf 0
    f32x4 a00 = *(const f32x4*)(asrc0);
    f32x4 a01 = *(const f32x4*)(asrc0 + 4);
    f32x4 a10 = *(const f32x4*)(asrc1);
    f32x4 a11 = *(const f32x4*)(asrc1 + 4);
    GLD16(bsrc0, &Bs[0][lo0]);
    GLD16(bsrc1, &Bs[0][lo1]);

    #pragma unroll 2
    for (int it = 0; it < 16; ++it) {
        const int cur = it & 1, nxt = cur ^ 1;
        {   // stage A (prefetched regs) into buf cur
            u16x8 h0, h1;
            h0[0]=f2h(a00[0]); h0[1]=f2h(a00[1]); h0[2]=f2h(a00[2]); h0[3]=f2h(a00[3]);
            h0[4]=f2h(a01[0]); h0[5]=f2h(a01[1]); h0[6]=f2h(a01[2]); h0[7]=f2h(a01[3]);
            h1[0]=f2h(a10[0]); h1[1]=f2h(a10[1]); h1[2]=f2h(a10[2]); h1[3]=f2h(a10[3]);
            h1[4]=f2h(a11[0]); h1[5]=f2h(a11[1]); h1[6]=f2h(a11[2]); h1[7]=f2h(a11[3]);
            *(u16x8*)&As[cur][lo0] = h0;
            *(u16x8*)&As[cur][lo1] = h1;
        }
        __syncthreads();
        if (it < 15) {  // issue next-iter loads; latency hidden under MFMA below
            const int kn = (it + 1) * 32;
            a00 = *(const f32x4*)(asrc0 + kn);
            a01 = *(const f32x4*)(asrc0 + kn + 4);
            a10 = *(const f32x4*)(asrc1 + kn);
            a11 = *(const f32x4*)(asrc1 + kn + 4);
            GLD16(bsrc0 + kn, &Bs[nxt][lo0]);
            GLD16(bsrc1 + kn, &Bs[nxt][lo1]);
        }
        {
            f16x8 af[4], bfr[4];
            #pragma unroll
            for (int mt = 0; mt < 4; ++mt)
                af[mt] = *(const f16x8*)&As[cur][(wr*64 + mt*16 + al) * 32 + g*8];
            #pragma unroll
            for (int nt = 0; nt < 4; ++nt)
                bfr[nt] = *(const f16x8*)&Bs[cur][(wc*64 + nt*16 + al) * 32 + g*8];
            #pragma unroll
            for (int mt = 0; mt < 4; ++mt)
                #pragma unroll
                for (int nt = 0; nt < 4; ++nt)
                    acc[mt][nt] = __builtin_amdgcn_mfma_f32_16x16x32_f16(af[mt], bfr[nt], acc[mt][nt], 0, 0, 0);
        }
    }
    #pragma unroll
    for (int nt = 0; nt < 4; ++nt) {
        int col = n0 + wc*64 + nt*16 + al;
        float bv = bias[col];
        #pragma unroll
        for (int mt = 0; mt < 4; ++mt)
            #pragma unroll
            for (int rg = 0; rg < 4; ++rg) {
                size_t row = (size_t)(m0 + wr*64 + mt*16 + g*4 + rg);
                outp[row * 512 + col] = f2h((acc[mt][nt][rg] + bv) * scale);
            }
    }
}

// ---------------- V GEMM: same dbuf pipeline; V^T epilogue [win][h][d][k]
__global__ __launch_bounds__(256, 4) void gemm_v(
    const float* __restrict__ A, const u16* __restrict__ BT,
    const float* __restrict__ bias, u16* __restrict__ outp)
{
    __shared__ u16 As[2][128 * 32];
    __shared__ u16 Bs[2][128 * 32];
    const int tid = threadIdx.x;
    const int l = tid & 63, w = tid >> 6;
    const int al = l & 15, g = l >> 4;
    const int wr = w >> 1, wc = w & 1;
    const int wg = swz4096(blockIdx.x);
    const int n0 = (wg & 3) * 128, m0 = (wg >> 2) * 128;
    const int srow = tid >> 2, sc8 = (tid & 3) * 8;
    const float* asrc0 = A  + (size_t)(m0 + srow) * 512 + sc8;
    const float* asrc1 = A  + (size_t)(m0 + 64 + srow) * 512 + sc8;
    const u16*   bsrc0 = BT + (size_t)(n0 + srow) * 512 + sc8;
    const u16*   bsrc1 = BT + (size_t)(n0 + 64 + srow) * 512 + sc8;
    const int lo0 = srow * 32 + sc8, lo1 = (64 + srow) * 32 + sc8;
    f32x4 acc[4][4] = {};

    f32x4 a00 = *(const f32x4*)(asrc0);
    f32x4 a01 = *(const f32x4*)(asrc0 + 4);
    f32x4 a10 = *(const f32x4*)(asrc1);
    f32x4 a11 = *(const f32x4*)(asrc1 + 4);
    GLD16(bsrc0, &Bs[0][lo0]);
    GLD16(bsrc1, &Bs[0][lo1]);

    #pragma unroll 2
    for (int it = 0; it < 16; ++it) {
        const int cur = it & 1, nxt = cur ^ 1;
        {
            u16x8 h0, h1;
            h0[0]=f2h(a00[0]); h0[1]=f2h(a00[1]); h0[2]=f2h(a00[2]); h0[3]=f2h(a00[3]);
            h0[4]=f2h(a01[0]); h0[5]=f2h(a01[1]); h0[6]=f2h(a01[2]); h0[7]=f2h(a01[3]);
            h1[0]=f2h(a10[0]); h1[1]=f2h(a10[1]); h1[2]=f2h(a10[2]); h1[3]=f2h(a10[3]);
            h1[4]=f2h(a11[0]); h1[5]=f2h(a11[1]); h1[6]=f2h(a11[2]); h1[7]=f2h(a11[3]);
            *(u16x8*)&As[cur][lo0] = h0;
            *(u16x8*)&As[cur][lo1] = h1;
        }
        __syncthreads();
        if (it < 15) {
            const int kn = (it + 1) * 32;
            a00 = *(const f32x4*)(asrc0 + kn);
            a01 = *(const f32x4*)(asrc0 + kn + 4);
            a10 = *(const f32x4*)(asrc1 + kn);
            a11 = *(const f32x4*)(asrc1 + kn + 4);
            GLD16(bsrc0 + kn, &Bs[nxt][lo0]);
            GLD16(bsrc1 + kn, &Bs[nxt][lo1]);
        }
        {
            f16x8 af[4], bfr[4];
            #pragma unroll
            for (int mt = 0; mt < 4; ++mt)
                af[mt] = *(const f16x8*)&As[cur][(wr*64 + mt*16 + al) * 32 + g*8];
            #pragma unroll
            for (int nt = 0; nt < 4; ++nt)
                bfr[nt] = *(const f16x8*)&Bs[cur][(wc*64 + nt*16 + al) * 32 + g*8];
            #pragma unroll
            for (int mt = 0; mt < 4; ++mt)
                #pragma unroll
                for (int nt = 0; nt < 4; ++nt)
                    acc[mt][nt] = __builtin_amdgcn_mfma_f32_16x16x32_f16(af[mt], bfr[nt], acc[mt][nt], 0, 0, 0);
        }
    }
    #pragma unroll
    for (int nt = 0; nt < 4; ++nt) {
        int col = n0 + wc*64 + nt*16 + al;
        int hh_ = col >> 5, d = col & 31;
        float bv = bias[col];
        #pragma unroll
        for (int mt = 0; mt < 4; ++mt) {
            int row0 = m0 + wr*64 + mt*16 + g*4;
            int window = row0 >> 6, k0 = row0 & 63;
            size_t off = ((size_t)window << 15) + (hh_ << 11) + (d << 6) + k0;
            u16x4 hv;
            #pragma unroll
            for (int rg = 0; rg < 4; ++rg)
                hv[rg] = f2h(acc[mt][nt][rg] + bv);
            *(u16x4*)(outp + off) = hv;
        }
    }
}

// ---------------- proj GEMM: BK=32, dbuf 1-barrier, A+B via global_load_lds
__global__ __launch_bounds__(256, 4) void gemm_proj(
    const u16* __restrict__ A1, const u16* __restrict__ BT,
    const float* __restrict__ bias, float* __restrict__ outp)
{
    __shared__ u16 As[2][128 * 32];
    __shared__ u16 Bs[2][128 * 32];
    const int tid = threadIdx.x;
    const int l = tid & 63, w = tid >> 6;
    const int al = l & 15, g = l >> 4;
    const int wr = w >> 1, wc = w & 1;
    const int wg = swz4096(blockIdx.x);
    const int n0 = (wg & 3) * 128, m0 = (wg >> 2) * 128;
    const int srow = tid >> 2, sc8 = (tid & 3) * 8;
    const u16* asrc0 = A1 + (size_t)(m0 + srow) * 512 + sc8;
    const u16* asrc1 = A1 + (size_t)(m0 + 64 + srow) * 512 + sc8;
    const u16* bsrc0 = BT + (size_t)(n0 + srow) * 512 + sc8;
    const u16* bsrc1 = BT + (size_t)(n0 + 64 + srow) * 512 + sc8;
    const int lo0 = srow * 32 + sc8, lo1 = (64 + srow) * 32 + sc8;
    f32x4 acc[4][4] = {};

    GLD16(asrc0, &As[0][lo0]);
    GLD16(asrc1, &As[0][lo1]);
    GLD16(bsrc0, &Bs[0][lo0]);
    GLD16(bsrc1, &Bs[0][lo1]);

    #pragma unroll 2
    for (int it = 0; it < 16; ++it) {
        const int cur = it & 1, nxt = cur ^ 1;
        __syncthreads();
        if (it < 15) {
            const int kn = (it + 1) * 32;
            GLD16(asrc0 + kn, &As[nxt][lo0]);
            GLD16(asrc1 + kn, &As[nxt][lo1]);
            GLD16(bsrc0 + kn, &Bs[nxt][lo0]);
            GLD16(bsrc1 + kn, &Bs[nxt][lo1]);
        }
        {
            f16x8 af[4], bfr[4];
            #pragma unroll
            for (int mt = 0; mt < 4; ++mt)
                af[mt] = *(const f16x8*)&As[cur][(wr*64 + mt*16 + al) * 32 + g*8];
            #pragma unroll
            for (int nt = 0; nt < 4; ++nt)
                bfr[nt] = *(const f16x8*)&Bs[cur][(wc*64 + nt*16 + al) * 32 + g*8];
            #pragma unroll
            for (int mt = 0; mt < 4; ++mt)
                #pragma unroll
                for (int nt = 0; nt < 4; ++nt)
                    acc[mt][nt] = __builtin_amdgcn_mfma_f32_16x16x32_f16(af[mt], bfr[nt], acc[mt][nt], 0, 0, 0);
        }
    }
    #pragma unroll
    for (int nt = 0; nt < 4; ++nt) {
        int col = n0 + wc*64 + nt*16 + al;
        float bv = bias[col];
        #pragma unroll
        for (int mt = 0; mt < 4; ++mt)
            #pragma unroll
            for (int rg = 0; rg < 4; ++rg) {
                size_t row = (size_t)(m0 + wr*64 + mt*16 + g*4 + rg);
                outp[row * 512 + col] = acc[mt][nt][rg] + bv;
            }
    }
}

// ---------------- fused window attention (fp16, phase-grouped) ----------------
// grid (2048, 4). Window remap: XCD x only handles windows with (b&63)>>3 == x,
// so each XCD's cmb slice (8 wmods * 256KB = 2MB) stays L2-resident.
__global__ __launch_bounds__(256) void attn64(
    const u16* __restrict__ Q, const u16* __restrict__ Kb,
    const u16* __restrict__ Vth,
    const float* __restrict__ cmb,
    u16* __restrict__ Oout)
{
    __shared__ u16 Ph[4][64 * 72];
    const int bid = blockIdx.x;
    const int xcd = bid & 7, idx = bid >> 3;
    const int b = ((idx >> 3) << 6) | (xcd << 3) | (idx & 7);   // bijective
    const int tid = threadIdx.x;
    const int l = tid & 63, w = tid >> 6;
    const int al = l & 15, g = l >> 4;
    const size_t rbase = (size_t)b * 64;
    const int h = blockIdx.y * 4 + w;
    const int co = h * 32;

    // V^T fragments first (latency hidden under QK+softmax)
    const u16* vth = Vth + ((size_t)b << 15) + (h << 11);
    f16x8 vhf[2][2];
    #pragma unroll
    for (int kt = 0; kt < 2; ++kt)
        #pragma unroll
        for (int dt = 0; dt < 2; ++dt) {
            int voff = ((dt*16 + al) << 6) + kt*32 + g*8;
            vhf[kt][dt] = *(const f16x8*)(vth + voff);
        }

    f16x8 qf[4], kf[4];
    #pragma unroll
    for (int t = 0; t < 4; ++t) {
        qf[t] = *(const f16x8*)(Q  + (rbase + t*16 + al) * 512 + co + g*8);
        kf[t] = *(const f16x8*)(Kb + (rbase + t*16 + al) * 512 + co + g*8);
    }
    f32x4 s[4][4] = {};
    #pragma unroll
    for (int mt = 0; mt < 4; ++mt)
        #pragma unroll
        for (int nt = 0; nt < 4; ++nt)
            s[mt][nt] = __builtin_amdgcn_mfma_f32_16x16x32_f16(qf[mt], kf[nt], s[mt][nt], 0, 0, 0);

    const float* cp = cmb + ((((size_t)(b & 63)) * 16 + h) << 12);
    #pragma unroll
    for (int mt = 0; mt < 4; ++mt)
        #pragma unroll
        for (int nt = 0; nt < 4; ++nt) {
            f32x4 c4 = *(const f32x4*)(cp + ((nt*16 + al) << 6) + mt*16 + g*4);
            #pragma unroll
            for (int rg = 0; rg < 4; ++rg) s[mt][nt][rg] += c4[rg];
        }

    // ---- softmax for all 4 mt (registers only), then one LDS phase ----
    f32x4 sm[4];
    #pragma unroll
    for (int mt = 0; mt < 4; ++mt) {
        f32x4 m4 = s[mt][0];
        #pragma unroll
        for (int nt = 1; nt < 4; ++nt)
            #pragma unroll
            for (int c = 0; c < 4; ++c) m4[c] = fmaxf(m4[c], s[mt][nt][c]);
        #pragma unroll
        for (int d = 1; d < 16; d <<= 1)
            #pragma unroll
            for (int c = 0; c < 4; ++c) m4[c] = fmaxf(m4[c], shflx(m4[c], d));
        #pragma unroll
        for (int nt = 0; nt < 4; ++nt)
            #pragma unroll
            for (int rg = 0; rg < 4; ++rg)
                s[mt][nt][rg] = exp2f((s[mt][nt][rg] - m4[rg]) * LOG2E);
        f32x4 s4 = s[mt][0];
        #pragma unroll
        for (int nt = 1; nt < 4; ++nt) s4 += s[mt][nt];
        #pragma unroll
        for (int d = 1; d < 16; d <<= 1)
            #pragma unroll
            for (int c = 0; c < 4; ++c) s4[c] += shflx(s4[c], d);
        sm[mt] = s4;
    }

    // write all of P (per-wave buffer; same-wave read below, no barrier)
    #pragma unroll
    for (int mt = 0; mt < 4; ++mt)
        #pragma unroll
        for (int nt = 0; nt < 4; ++nt)
            #pragma unroll
            for (int rg = 0; rg < 4; ++rg) {
                int off = (mt*16 + g*4 + rg) * 72 + nt*16 + al;
                Ph[w][off] = f2h(s[mt][nt][rg]);
            }

    // ---- PV for all mt, back-to-back MFMAs ----
    #pragma unroll
    for (int mt = 0; mt < 4; ++mt) {
        f16x8 pah[2];
        #pragma unroll
        for (int kt = 0; kt < 2; ++kt)
            pah[kt] = *(const f16x8*)&Ph[w][(mt*16 + al) * 72 + kt*32 + g*8];
        f32x4 o[2] = {};
        #pragma unroll
        for (int dt = 0; dt < 2; ++dt)
            #pragma unroll
            for (int kt = 0; kt < 2; ++kt)
                o[dt] = __builtin_amdgcn_mfma_f32_16x16x32_f16(pah[kt], vhf[kt][dt], o[dt], 0, 0, 0);
        #pragma unroll
        for (int dt = 0; dt < 2; ++dt)
            #pragma unroll
            for (int rg = 0; rg < 4; ++rg) {
                float inv = __builtin_amdgcn_rcpf(sm[mt][rg]);
                float v = o[dt][rg] * inv;
                size_t off = (rbase + mt*16 + g*4 + rg) * 512 + co + dt*16 + al;
                Oout[off] = f2h(v);
            }
    }
}

// ---------------- launch ----------------
extern "C" void kernel_launch(void* const* d_in, const int* in_sizes, int n_in,
                              void* d_out, int out_size, void* d_ws, size_t ws_size,
                              hipStream_t stream)
{
    const float* x      = (const float*)d_in[0];
    const float* y      = (const float*)d_in[1];
    const float* mask   = (const float*)d_in[2];
    const float* W_q    = (const float*)d_in[3];
    const float* b_q    = (const float*)d_in[4];
    const float* W_kv   = (const float*)d_in[5];
    const float* b_kv   = (const float*)d_in[6];
    const float* W_proj = (const float*)d_in[7];
    const float* b_proj = (const float*)d_in[8];
    const float* table  = (const float*)d_in[9];

    char* ws = (char*)d_ws;
    const size_t SEG = (size_t)MROWS * 512 * sizeof(u16);   // 128 MB
    u16* Qs     = (u16*)(ws);              // aliased by O after attention
    u16* Ks     = (u16*)(ws + SEG);
    u16* Vth    = (u16*)(ws + 2 * SEG);    // V^T [win][h][d][k], fp16
    u16* wqT    = (u16*)(ws + 3 * SEG);
    u16* wkvKT  = wqT    + 512 * 512;
    u16* wkvVT  = wkvKT  + 512 * 512;
    u16* wprT   = wkvVT  + 512 * 512;
    float* cmb  = (float*)(wprT + 512 * 512);   // 64*16*4096*4B = 16 MB

    wt_f16<<<1024, 256, 0, stream>>>(W_q, 512, 0, wqT, 512);
    wt_f16<<<1024, 256, 0, stream>>>(W_kv, 1024, 0, wkvKT, 512);
    wt_f16<<<1024, 256, 0, stream>>>(W_kv, 1024, 512, wkvVT, 512);
    wt_f16<<<1024, 256, 0, stream>>>(W_proj, 512, 0, wprT, 512);
    cmb_pre<<<dim3(64, 16), 256, 0, stream>>>(table, mask, cmb);

    gemm_qk<<<4096, 256, 0, stream>>>(x, wqT, b_q, Qs, QSCALE);
    gemm_qk<<<4096, 256, 0, stream>>>(y, wkvKT, b_kv, Ks, 1.0f);
    gemm_v<<<4096, 256, 0, stream>>>(y, wkvVT, b_kv + 512, Vth);
    attn64<<<dim3(2048, 4), 256, 0, stream>>>(Qs, Ks, Vth, cmb, Qs);
    gemm_proj<<<4096, 256, 0, stream>>>(Qs, wprT, b_proj, (float*)d_out);
}